// Round 1
// baseline (17611.317 us; speedup 1.0000x reference)
//
#include <hip/hip_runtime.h>
#include <hip/hip_bf16.h>
#include <math.h>

// Problem constants
#define BB 2
#define SS 1024
#define LL 12
#define HH 12
#define DD 768
#define FFF 3072
#define DHH 64
#define MOTIF 414
#define HCAT (DD + MOTIF)   // 1182
#define W1 256
#define NEGV -1e9f
#define EPS 1e-5f
#define SCALE 0.125f        // 1/sqrt(64)

// ---------------- block reduction helpers (blockDim.x == 256) ----------------
__device__ __forceinline__ float block_reduce_sum(float v, float* red) {
    int t = threadIdx.x;
    red[t] = v; __syncthreads();
    #pragma unroll
    for (int s = 128; s > 0; s >>= 1) {
        if (t < s) red[t] += red[t + s];
        __syncthreads();
    }
    float r = red[0]; __syncthreads();
    return r;
}

__device__ __forceinline__ float block_reduce_max(float v, float* red) {
    int t = threadIdx.x;
    red[t] = v; __syncthreads();
    #pragma unroll
    for (int s = 128; s > 0; s >>= 1) {
        if (t < s) red[t] = fmaxf(red[t], red[t + s]);
        __syncthreads();
    }
    float r = red[0]; __syncthreads();
    return r;
}

// ---------------- embedding + LN ----------------
__global__ __launch_bounds__(256) void embed_ln_kernel(
    const int* __restrict__ ids, const float* __restrict__ ew,
    const float* __restrict__ ep, const float* __restrict__ et,
    const float* __restrict__ gs, const float* __restrict__ gb,
    float* __restrict__ X) {
    __shared__ float red[256];
    int row = blockIdx.x;            // b*S + s
    int s = row % SS;
    int id = ids[row];
    int t = threadIdx.x;
    float v[3];
    float sum = 0.f;
    #pragma unroll
    for (int i = 0; i < 3; ++i) {
        int d = t + 256 * i;
        float x = ew[(size_t)id * DD + d] + ep[(size_t)(s + 2) * DD + d] + et[d];
        v[i] = x; sum += x;
    }
    sum = block_reduce_sum(sum, red);
    float m = sum * (1.f / DD);
    float sq = 0.f;
    #pragma unroll
    for (int i = 0; i < 3; ++i) { float c = v[i] - m; sq += c * c; }
    sq = block_reduce_sum(sq, red);
    float inv = rsqrtf(sq * (1.f / DD) + EPS);
    #pragma unroll
    for (int i = 0; i < 3; ++i) {
        int d = t + 256 * i;
        X[(size_t)row * DD + d] = (v[i] - m) * inv * gs[d] + gb[d];
    }
}

// ---------------- residual add + LN:  X = LN(X + T) ----------------
__global__ __launch_bounds__(256) void add_ln_kernel(
    float* __restrict__ X, const float* __restrict__ T,
    const float* __restrict__ gs, const float* __restrict__ gb) {
    __shared__ float red[256];
    int row = blockIdx.x;
    int t = threadIdx.x;
    float v[3];
    float sum = 0.f;
    #pragma unroll
    for (int i = 0; i < 3; ++i) {
        int d = t + 256 * i;
        float x = X[(size_t)row * DD + d] + T[(size_t)row * DD + d];
        v[i] = x; sum += x;
    }
    sum = block_reduce_sum(sum, red);
    float m = sum * (1.f / DD);
    float sq = 0.f;
    #pragma unroll
    for (int i = 0; i < 3; ++i) { float c = v[i] - m; sq += c * c; }
    sq = block_reduce_sum(sq, red);
    float inv = rsqrtf(sq * (1.f / DD) + EPS);
    #pragma unroll
    for (int i = 0; i < 3; ++i) {
        int d = t + 256 * i;
        X[(size_t)row * DD + d] = (v[i] - m) * inv * gs[d] + gb[d];
    }
}

// ---------------- generic f32 GEMM: C[M,N] = A[M,K] @ W[K,N] + bias ----------------
// ACT: 0 = none, 1 = exact gelu
template <int ACT>
__global__ __launch_bounds__(256) void gemm_kernel(
    const float* __restrict__ A, const float* __restrict__ W,
    const float* __restrict__ bias, float* __restrict__ C,
    int M, int N, int K) {
    __shared__ float As[16][64];
    __shared__ float Bs[16][64];
    int t = threadIdx.x;
    int bm = blockIdx.y * 64;
    int bn = blockIdx.x * 64;
    int tx = t & 15, ty = t >> 4;
    int arow = t >> 2;            // 0..63
    int acol = (t & 3) * 4;       // 0,4,8,12
    int brow = t >> 4;            // 0..15
    int bcol = (t & 15) * 4;      // 0..60
    float acc[4][4] = {{0.f}};
    for (int k0 = 0; k0 < K; k0 += 16) {
        float4 av = *reinterpret_cast<const float4*>(A + (size_t)(bm + arow) * K + k0 + acol);
        As[acol + 0][arow] = av.x;
        As[acol + 1][arow] = av.y;
        As[acol + 2][arow] = av.z;
        As[acol + 3][arow] = av.w;
        float4 wv = *reinterpret_cast<const float4*>(W + (size_t)(k0 + brow) * N + bn + bcol);
        *reinterpret_cast<float4*>(&Bs[brow][bcol]) = wv;
        __syncthreads();
        #pragma unroll
        for (int kk = 0; kk < 16; ++kk) {
            float a_[4], b_[4];
            #pragma unroll
            for (int i2 = 0; i2 < 4; ++i2) a_[i2] = As[kk][ty * 4 + i2];
            #pragma unroll
            for (int j2 = 0; j2 < 4; ++j2) b_[j2] = Bs[kk][tx * 4 + j2];
            #pragma unroll
            for (int i2 = 0; i2 < 4; ++i2)
                #pragma unroll
                for (int j2 = 0; j2 < 4; ++j2)
                    acc[i2][j2] += a_[i2] * b_[j2];
        }
        __syncthreads();
    }
    #pragma unroll
    for (int i2 = 0; i2 < 4; ++i2) {
        int m = bm + ty * 4 + i2;
        #pragma unroll
        for (int j2 = 0; j2 < 4; ++j2) {
            int n = bn + tx * 4 + j2;
            float c = acc[i2][j2] + bias[n];
            if (ACT == 1) c = 0.5f * c * (1.f + erff(c * 0.70710678118654752f));
            C[(size_t)m * N + n] = c;
        }
    }
}

// ---------------- tiny GEMV for the global query: QG[b,:] = X[b,0,:] @ Wqg + bqg ----------------
__global__ __launch_bounds__(256) void qg_kernel(
    const float* __restrict__ X, const float* __restrict__ W,
    const float* __restrict__ bias, float* __restrict__ QG) {
    int b = blockIdx.x / 3;
    int n = (blockIdx.x % 3) * 256 + threadIdx.x;
    const float* xr = X + (size_t)b * SS * DD;   // row 0 of batch b
    float acc = bias[n];
    for (int k = 0; k < DD; ++k) acc += xr[k] * W[(size_t)k * DD + n];
    QG[(size_t)b * DD + n] = acc;
}

// ---------------- local (sliding-window + global-key) attention ----------------
// one block per (b, h, i); writes AO[b, i, h*64 + d]
__global__ __launch_bounds__(256) void attn_local_kernel(
    const float* __restrict__ Q, const float* __restrict__ K,
    const float* __restrict__ V, const int* __restrict__ mask,
    float* __restrict__ AO) {
    __shared__ float qv[64];
    __shared__ float sc[514];
    __shared__ float red[256];
    __shared__ float part[4][64];
    int bid = blockIdx.x;
    int i = bid % SS;
    int h = (bid / SS) % HH;
    int b = bid / (SS * HH);
    int t = threadIdx.x;
    if (t < 64) qv[t] = Q[((size_t)(b * SS + i)) * DD + h * 64 + t];
    __syncthreads();
    int jlo = i - W1; if (jlo < 0) jlo = 0;
    int jhi = i + W1; if (jhi > SS - 1) jhi = SS - 1;
    int ext = (jlo > 0) ? 1 : 0;    // global key j=0 if not already in band
    int cnt = jhi - jlo + 1 + ext;
    for (int idx = t; idx < cnt; idx += 256) {
        int j = (idx < ext) ? 0 : (jlo + idx - ext);
        const float* kp = K + ((size_t)(b * SS + j)) * DD + h * 64;
        float acc = 0.f;
        #pragma unroll
        for (int d = 0; d < 64; d += 4) {
            float4 k4 = *reinterpret_cast<const float4*>(kp + d);
            acc += qv[d] * k4.x + qv[d + 1] * k4.y + qv[d + 2] * k4.z + qv[d + 3] * k4.w;
        }
        sc[idx] = mask[b * SS + j] ? acc * SCALE : NEGV;
    }
    __syncthreads();
    float mx = -1e30f;
    for (int idx = t; idx < cnt; idx += 256) mx = fmaxf(mx, sc[idx]);
    mx = block_reduce_max(mx, red);
    float lsum = 0.f;
    for (int idx = t; idx < cnt; idx += 256) {
        float e = expf(sc[idx] - mx);
        sc[idx] = e; lsum += e;
    }
    lsum = block_reduce_sum(lsum, red);   // includes syncthreads; sc[] visible
    int g = t >> 6, d = t & 63;
    float acc = 0.f;
    for (int idx = g; idx < cnt; idx += 4) {
        int j = (idx < ext) ? 0 : (jlo + idx - ext);
        acc += sc[idx] * V[((size_t)(b * SS + j)) * DD + h * 64 + d];
    }
    part[g][d] = acc;
    __syncthreads();
    if (g == 0) {
        float o = (part[0][d] + part[1][d] + part[2][d] + part[3][d]) / lsum;
        AO[((size_t)(b * SS + i)) * DD + h * 64 + d] = o;
    }
}

// ---------------- global (CLS) attention: overwrites AO row 0 ----------------
// one block per (b, h)
__global__ __launch_bounds__(256) void attn_global_kernel(
    const float* __restrict__ QG, const float* __restrict__ KG,
    const float* __restrict__ VG, const int* __restrict__ mask,
    float* __restrict__ AO) {
    __shared__ float qv[64];
    __shared__ float sc[SS];
    __shared__ float red[256];
    __shared__ float part[4][64];
    int b = blockIdx.x / HH;
    int h = blockIdx.x % HH;
    int t = threadIdx.x;
    if (t < 64) qv[t] = QG[(size_t)b * DD + h * 64 + t];
    __syncthreads();
    for (int j = t; j < SS; j += 256) {
        const float* kp = KG + ((size_t)(b * SS + j)) * DD + h * 64;
        float acc = 0.f;
        #pragma unroll
        for (int d = 0; d < 64; d += 4) {
            float4 k4 = *reinterpret_cast<const float4*>(kp + d);
            acc += qv[d] * k4.x + qv[d + 1] * k4.y + qv[d + 2] * k4.z + qv[d + 3] * k4.w;
        }
        sc[j] = mask[b * SS + j] ? acc * SCALE : NEGV;
    }
    __syncthreads();
    float mx = -1e30f;
    for (int j = t; j < SS; j += 256) mx = fmaxf(mx, sc[j]);
    mx = block_reduce_max(mx, red);
    float lsum = 0.f;
    for (int j = t; j < SS; j += 256) {
        float e = expf(sc[j] - mx);
        sc[j] = e; lsum += e;
    }
    lsum = block_reduce_sum(lsum, red);
    int g = t >> 6, d = t & 63;
    float acc = 0.f;
    for (int j = g; j < SS; j += 4)
        acc += sc[j] * VG[((size_t)(b * SS + j)) * DD + h * 64 + d];
    part[g][d] = acc;
    __syncthreads();
    if (g == 0) {
        float o = (part[0][d] + part[1][d] + part[2][d] + part[3][d]) / lsum;
        AO[((size_t)(b * SS + 0)) * DD + h * 64 + d] = o;
    }
}

// ---------------- classification head ----------------
__global__ __launch_bounds__(256) void head_kernel(
    const float* __restrict__ X, const float* __restrict__ motif,
    const float* __restrict__ Wd, const float* __restrict__ bd,
    const float* __restrict__ Wp, const float* __restrict__ bp,
    float* __restrict__ out) {
    __shared__ float hc[HCAT];
    __shared__ float dv[DD];
    __shared__ float red[256];
    int b = blockIdx.x;
    int t = threadIdx.x;
    for (int i = t; i < DD; i += 256) hc[i] = X[(size_t)b * SS * DD + i];
    for (int i = t; i < MOTIF; i += 256) hc[DD + i] = motif[(size_t)b * MOTIF + i];
    __syncthreads();
    for (int j = t; j < DD; j += 256) {
        float acc = bd[j];
        for (int k = 0; k < HCAT; ++k) acc += hc[k] * Wd[(size_t)k * DD + j];
        dv[j] = tanhf(acc);
    }
    __syncthreads();
    float a0 = 0.f, a1 = 0.f;
    for (int k = t; k < DD; k += 256) {
        a0 += dv[k] * Wp[k * 2 + 0];
        a1 += dv[k] * Wp[k * 2 + 1];
    }
    a0 = block_reduce_sum(a0, red);
    a1 = block_reduce_sum(a1, red);
    if (t == 0) {
        out[b * 2 + 0] = a0 + bp[0];
        out[b * 2 + 1] = a1 + bp[1];
    }
}

// ---------------- host launch ----------------
extern "C" void kernel_launch(void* const* d_in, const int* in_sizes, int n_in,
                              void* d_out, int out_size, void* d_ws, size_t ws_size,
                              hipStream_t stream) {
    const int*   input_ids = (const int*)d_in[0];
    const int*   attn_mask = (const int*)d_in[1];
    const float* motif     = (const float*)d_in[2];
    const float* emb_word  = (const float*)d_in[3];
    const float* emb_pos   = (const float*)d_in[4];
    const float* emb_type  = (const float*)d_in[5];
    const float* emb_ln_s  = (const float*)d_in[6];
    const float* emb_ln_b  = (const float*)d_in[7];
    const float* Wq  = (const float*)d_in[8];
    const float* bq  = (const float*)d_in[9];
    const float* Wk  = (const float*)d_in[10];
    const float* bk  = (const float*)d_in[11];
    const float* Wv  = (const float*)d_in[12];
    const float* bv  = (const float*)d_in[13];
    const float* Wqg = (const float*)d_in[14];
    const float* bqg = (const float*)d_in[15];
    const float* Wkg = (const float*)d_in[16];
    const float* bkg = (const float*)d_in[17];
    const float* Wvg = (const float*)d_in[18];
    const float* bvg = (const float*)d_in[19];
    const float* Wo  = (const float*)d_in[20];
    const float* bo  = (const float*)d_in[21];
    const float* ln1_s = (const float*)d_in[22];
    const float* ln1_b = (const float*)d_in[23];
    const float* Wi  = (const float*)d_in[24];
    const float* bi  = (const float*)d_in[25];
    const float* Wo2 = (const float*)d_in[26];
    const float* bo2 = (const float*)d_in[27];
    const float* ln2_s = (const float*)d_in[28];
    const float* ln2_b = (const float*)d_in[29];
    const float* head_Wd = (const float*)d_in[30];
    const float* head_bd = (const float*)d_in[31];
    const float* head_Wp = (const float*)d_in[32];
    const float* head_bp = (const float*)d_in[33];

    float* out = (float*)d_out;
    float* ws  = (float*)d_ws;

    const size_t ND = (size_t)BB * SS * DD;   // 1,572,864
    float* X  = ws;
    float* Qb = ws + 1 * ND;
    float* Kb = ws + 2 * ND;
    float* Vb = ws + 3 * ND;
    float* KG = ws + 4 * ND;
    float* VG = ws + 5 * ND;
    float* AO = ws + 6 * ND;
    float* QG = ws + 7 * ND;                  // B*D floats
    float* T1 = Qb;                            // aliases Q..KG: B*S*FF floats = 4*ND

    const int nrow = BB * SS;                 // 2048

    // embedding
    embed_ln_kernel<<<nrow, 256, 0, stream>>>(input_ids, emb_word, emb_pos, emb_type,
                                              emb_ln_s, emb_ln_b, X);

    dim3 g768(DD / 64, nrow / 64);            // 12 x 32
    dim3 gFF(FFF / 64, nrow / 64);            // 48 x 32

    for (int l = 0; l < LL; ++l) {
        const float* Wq_l  = Wq  + (size_t)l * DD * DD;
        const float* Wk_l  = Wk  + (size_t)l * DD * DD;
        const float* Wv_l  = Wv  + (size_t)l * DD * DD;
        const float* Wqg_l = Wqg + (size_t)l * DD * DD;
        const float* Wkg_l = Wkg + (size_t)l * DD * DD;
        const float* Wvg_l = Wvg + (size_t)l * DD * DD;
        const float* Wo_l  = Wo  + (size_t)l * DD * DD;
        const float* Wi_l  = Wi  + (size_t)l * DD * FFF;
        const float* Wo2_l = Wo2 + (size_t)l * FFF * DD;

        gemm_kernel<0><<<g768, 256, 0, stream>>>(X, Wq_l, bq + l * DD, Qb, nrow, DD, DD);
        gemm_kernel<0><<<g768, 256, 0, stream>>>(X, Wk_l, bk + l * DD, Kb, nrow, DD, DD);
        gemm_kernel<0><<<g768, 256, 0, stream>>>(X, Wv_l, bv + l * DD, Vb, nrow, DD, DD);
        gemm_kernel<0><<<g768, 256, 0, stream>>>(X, Wkg_l, bkg + l * DD, KG, nrow, DD, DD);
        gemm_kernel<0><<<g768, 256, 0, stream>>>(X, Wvg_l, bvg + l * DD, VG, nrow, DD, DD);
        qg_kernel<<<BB * 3, 256, 0, stream>>>(X, Wqg_l, bqg + l * DD, QG);

        attn_local_kernel<<<BB * HH * SS, 256, 0, stream>>>(Qb, Kb, Vb, attn_mask, AO);
        attn_global_kernel<<<BB * HH, 256, 0, stream>>>(QG, KG, VG, attn_mask, AO);

        gemm_kernel<0><<<g768, 256, 0, stream>>>(AO, Wo_l, bo + l * DD, T1, nrow, DD, DD);
        add_ln_kernel<<<nrow, 256, 0, stream>>>(X, T1, ln1_s + l * DD, ln1_b + l * DD);

        gemm_kernel<1><<<gFF, 256, 0, stream>>>(X, Wi_l, bi + l * FFF, T1, nrow, FFF, DD);
        gemm_kernel<0><<<g768, 256, 0, stream>>>(T1, Wo2_l, bo2 + l * DD, AO, nrow, DD, FFF);
        add_ln_kernel<<<nrow, 256, 0, stream>>>(X, AO, ln2_s + l * DD, ln2_b + l * DD);
    }

    head_kernel<<<BB, 256, 0, stream>>>(X, motif, head_Wd, head_bd, head_Wp, head_bp, out);
}

// Round 2
// 5520.615 us; speedup vs baseline: 3.1901x; 3.1901x over previous
//
#include <hip/hip_runtime.h>
#include <math.h>

typedef unsigned short u16;
typedef __attribute__((ext_vector_type(8))) short short8;   // 8 bf16 (4 VGPRs)
typedef __attribute__((ext_vector_type(4))) float f32x4;

#define BB 2
#define SS 1024
#define LL 12
#define HH 12
#define DD 768
#define FFF 3072
#define MOTIF 414
#define HCAT (DD + MOTIF)
#define W1 256
#define NEGV -1e9f
#define EPS 1e-5f
#define SCALE 0.125f

// ---------- bf16 helpers ----------
__device__ __forceinline__ float bf2f(u16 u) {
    union { unsigned i; float f; } x; x.i = ((unsigned)u) << 16; return x.f;
}
__device__ __forceinline__ u16 f2bf(float f) {
    union { float f; unsigned i; } x; x.f = f;
    unsigned r = x.i + 0x7fffu + ((x.i >> 16) & 1u);   // RNE
    return (u16)(r >> 16);
}

// async global->LDS, 16B per lane; lds dest must be wave-uniform base
__device__ __forceinline__ void gld16(const u16* g, u16* l) {
    __builtin_amdgcn_global_load_lds((const __attribute__((address_space(1))) void*)g,
                                     (__attribute__((address_space(3))) void*)l, 16, 0, 0);
}

// ---------------- block reduction helpers (blockDim.x == 256) ----------------
__device__ __forceinline__ float block_reduce_sum(float v, float* red) {
    int t = threadIdx.x;
    red[t] = v; __syncthreads();
    #pragma unroll
    for (int s = 128; s > 0; s >>= 1) {
        if (t < s) red[t] += red[t + s];
        __syncthreads();
    }
    float r = red[0]; __syncthreads();
    return r;
}
__device__ __forceinline__ float block_reduce_max(float v, float* red) {
    int t = threadIdx.x;
    red[t] = v; __syncthreads();
    #pragma unroll
    for (int s = 128; s > 0; s >>= 1) {
        if (t < s) red[t] = fmaxf(red[t], red[t + s]);
        __syncthreads();
    }
    float r = red[0]; __syncthreads();
    return r;
}

// ---------------- embedding + LN (writes f32 X and bf16 Xb) ----------------
__global__ __launch_bounds__(256) void embed_ln_kernel(
    const int* __restrict__ ids, const float* __restrict__ ew,
    const float* __restrict__ ep, const float* __restrict__ et,
    const float* __restrict__ gs, const float* __restrict__ gb,
    float* __restrict__ X, u16* __restrict__ Xb) {
    __shared__ float red[256];
    int row = blockIdx.x;
    int s = row % SS;
    int id = ids[row];
    int t = threadIdx.x;
    float v[3];
    float sum = 0.f;
    #pragma unroll
    for (int i = 0; i < 3; ++i) {
        int d = t + 256 * i;
        float x = ew[(size_t)id * DD + d] + ep[(size_t)(s + 2) * DD + d] + et[d];
        v[i] = x; sum += x;
    }
    sum = block_reduce_sum(sum, red);
    float m = sum * (1.f / DD);
    float sq = 0.f;
    #pragma unroll
    for (int i = 0; i < 3; ++i) { float c = v[i] - m; sq += c * c; }
    sq = block_reduce_sum(sq, red);
    float inv = rsqrtf(sq * (1.f / DD) + EPS);
    #pragma unroll
    for (int i = 0; i < 3; ++i) {
        int d = t + 256 * i;
        float o = (v[i] - m) * inv * gs[d] + gb[d];
        X[(size_t)row * DD + d] = o;
        Xb[(size_t)row * DD + d] = f2bf(o);
    }
}

// ---------------- residual add + LN: X = LN(X + T); also writes bf16 ----------------
__global__ __launch_bounds__(256) void add_ln_kernel(
    float* __restrict__ X, u16* __restrict__ Xb, const float* __restrict__ T,
    const float* __restrict__ gs, const float* __restrict__ gb) {
    __shared__ float red[256];
    int row = blockIdx.x;
    int t = threadIdx.x;
    float v[3];
    float sum = 0.f;
    #pragma unroll
    for (int i = 0; i < 3; ++i) {
        int d = t + 256 * i;
        float x = X[(size_t)row * DD + d] + T[(size_t)row * DD + d];
        v[i] = x; sum += x;
    }
    sum = block_reduce_sum(sum, red);
    float m = sum * (1.f / DD);
    float sq = 0.f;
    #pragma unroll
    for (int i = 0; i < 3; ++i) { float c = v[i] - m; sq += c * c; }
    sq = block_reduce_sum(sq, red);
    float inv = rsqrtf(sq * (1.f / DD) + EPS);
    #pragma unroll
    for (int i = 0; i < 3; ++i) {
        int d = t + 256 * i;
        float o = (v[i] - m) * inv * gs[d] + gb[d];
        X[(size_t)row * DD + d] = o;
        Xb[(size_t)row * DD + d] = f2bf(o);
    }
}

// ---------------- weight convert+transpose: W f32 [K,N] -> Wt bf16 [N,K] ----------------
__global__ __launch_bounds__(256) void convw_t(
    const float* __restrict__ W, u16* __restrict__ Wt, int Kd, int Nd) {
    __shared__ float Tt[32][33];
    int n0 = blockIdx.x * 32, k0 = blockIdx.y * 32;
    int t = threadIdx.x;
    int r = t >> 3, c = (t & 7) * 4;
    float4 v = *(const float4*)(W + (size_t)(k0 + r) * Nd + n0 + c);
    Tt[r][c] = v.x; Tt[r][c + 1] = v.y; Tt[r][c + 2] = v.z; Tt[r][c + 3] = v.w;
    __syncthreads();
    int n = t >> 3, k4 = (t & 7) * 4;
    unsigned lo = (unsigned)f2bf(Tt[k4][n])     | ((unsigned)f2bf(Tt[k4 + 1][n]) << 16);
    unsigned hi = (unsigned)f2bf(Tt[k4 + 2][n]) | ((unsigned)f2bf(Tt[k4 + 3][n]) << 16);
    uint2 wv; wv.x = lo; wv.y = hi;
    *(uint2*)&Wt[(size_t)(n0 + n) * Kd + k0 + k4] = wv;
}

// six 768x768 weights in one launch (z selects matrix)
__global__ __launch_bounds__(256) void conv6_kernel(
    const float* w0, const float* w1, const float* w2,
    const float* w3, const float* w4, const float* w5, u16* __restrict__ outb) {
    __shared__ float Tt[32][33];
    int z = blockIdx.z;
    const float* W = (z == 0) ? w0 : (z == 1) ? w1 : (z == 2) ? w2 : (z == 3) ? w3 : (z == 4) ? w4 : w5;
    u16* Wt = outb + (size_t)z * DD * DD;
    int n0 = blockIdx.x * 32, k0 = blockIdx.y * 32;
    int t = threadIdx.x;
    int r = t >> 3, c = (t & 7) * 4;
    float4 v = *(const float4*)(W + (size_t)(k0 + r) * DD + n0 + c);
    Tt[r][c] = v.x; Tt[r][c + 1] = v.y; Tt[r][c + 2] = v.z; Tt[r][c + 3] = v.w;
    __syncthreads();
    int n = t >> 3, k4 = (t & 7) * 4;
    unsigned lo = (unsigned)f2bf(Tt[k4][n])     | ((unsigned)f2bf(Tt[k4 + 1][n]) << 16);
    unsigned hi = (unsigned)f2bf(Tt[k4 + 2][n]) | ((unsigned)f2bf(Tt[k4 + 3][n]) << 16);
    uint2 wv; wv.x = lo; wv.y = hi;
    *(uint2*)&Wt[(size_t)(n0 + n) * DD + k0 + k4] = wv;
}

// ---------------- bf16 MFMA GEMM: C[M,N] = A[M,K] @ Wt[N,K]^T + bias ----------------
// ACT: 0 none, 1 exact gelu.  OBF: 1 -> bf16 out, 0 -> f32 out.
template <int ACT, int OBF>
__global__ __launch_bounds__(256) void gemm_bf16(
    const u16* __restrict__ A, const u16* __restrict__ Bt,
    const float* __restrict__ bias, void* __restrict__ Cout,
    int M, int N, int K) {
    __shared__ __align__(16) u16 As[128 * 32];
    __shared__ __align__(16) u16 Bs[128 * 32];
    int t = threadIdx.x, lane = t & 63, wv = t >> 6;
    int bm = blockIdx.y * 128, bn = blockIdx.x * 128;
    int wm = wv >> 1, wn = wv & 1;
    int h = lane >> 4, q15 = lane & 15;
    f32x4 acc[4][4];
    #pragma unroll
    for (int i = 0; i < 4; ++i)
        #pragma unroll
        for (int j = 0; j < 4; ++j) { acc[i][j][0] = 0.f; acc[i][j][1] = 0.f; acc[i][j][2] = 0.f; acc[i][j][3] = 0.f; }

    for (int k0 = 0; k0 < K; k0 += 32) {
        #pragma unroll
        for (int op = 0; op < 2; ++op) {
            int rc = wv * 32 + op * 16;
            int r = rc + (lane >> 2), s = lane & 3;
            gld16(A  + (size_t)(bm + r) * K + k0 + ((s ^ (r & 3)) * 8), &As[rc * 32]);
            gld16(Bt + (size_t)(bn + r) * K + k0 + ((s ^ (r & 3)) * 8), &Bs[rc * 32]);
        }
        __syncthreads();
        short8 af[4], bfr[4];
        #pragma unroll
        for (int mf = 0; mf < 4; ++mf) {
            int row = wm * 64 + mf * 16 + q15;
            af[mf] = *(const short8*)&As[row * 32 + ((h ^ (row & 3)) * 8)];
        }
        #pragma unroll
        for (int nf = 0; nf < 4; ++nf) {
            int row = wn * 64 + nf * 16 + q15;
            bfr[nf] = *(const short8*)&Bs[row * 32 + ((h ^ (row & 3)) * 8)];
        }
        #pragma unroll
        for (int mf = 0; mf < 4; ++mf)
            #pragma unroll
            for (int nf = 0; nf < 4; ++nf)
                acc[mf][nf] = __builtin_amdgcn_mfma_f32_16x16x32_bf16(af[mf], bfr[nf], acc[mf][nf], 0, 0, 0);
        __syncthreads();
    }
    float* Cf = (float*)Cout;
    u16*   Cb = (u16*)Cout;
    #pragma unroll
    for (int mf = 0; mf < 4; ++mf) {
        int mbase = bm + wm * 64 + mf * 16 + h * 4;
        #pragma unroll
        for (int nf = 0; nf < 4; ++nf) {
            int n = bn + wn * 64 + nf * 16 + q15;
            float bv = bias[n];
            #pragma unroll
            for (int rg = 0; rg < 4; ++rg) {
                float val = acc[mf][nf][rg] + bv;
                if (ACT == 1) val = 0.5f * val * (1.f + erff(val * 0.70710678118654752f));
                if (OBF) Cb[(size_t)(mbase + rg) * N + n] = f2bf(val);
                else     Cf[(size_t)(mbase + rg) * N + n] = val;
            }
        }
    }
}

// ---------------- fused local-window flash attention (MFMA) ----------------
// one block per (b, h, 64-query tile); Q,K,V bf16 row-major [B*S][768]
__global__ __launch_bounds__(256) void attn_local_mfma(
    const u16* __restrict__ Q, const u16* __restrict__ K,
    const u16* __restrict__ V, const int* __restrict__ mask,
    u16* __restrict__ AO) {
    __shared__ __align__(16) u16 Qs[64 * 64];
    __shared__ __align__(16) u16 Ks[64 * 64];
    __shared__ __align__(16) u16 Vst[64 * 64];   // transposed: [d][key], swizzled
    __shared__ __align__(16) u16 Pld[4][16 * 64];
    __shared__ float msk[64];
    int bid = blockIdx.x;
    int qt = bid & 15;
    int hh = (bid >> 4) % HH;
    int b  = bid / (16 * HH);
    int t = threadIdx.x, lane = t & 63, wv = t >> 6;
    int h = lane >> 4, q15 = lane & 15;
    int i0 = qt * 64;

    // stage Q (swizzled source, linear LDS dest)
    #pragma unroll
    for (int op = 0; op < 2; ++op) {
        int r = wv * 16 + op * 8 + (lane >> 3), s = lane & 7;
        gld16(Q + (size_t)(b * SS + i0 + r) * DD + hh * 64 + ((s ^ (r & 7)) * 8),
              &Qs[(wv * 16 + op * 8) * 64]);
    }
    __syncthreads();
    // hoist Q B-fragments (per-wave rows)
    short8 bq[2];
    {
        int qrow = wv * 16 + q15;
        #pragma unroll
        for (int ks = 0; ks < 2; ++ks)
            bq[ks] = *(const short8*)&Qs[qrow * 64 + (((ks * 4 + h) ^ (qrow & 7)) * 8)];
    }

    float mrun = -3e38f, lrun = 0.f;
    f32x4 o[4];
    #pragma unroll
    for (int nf = 0; nf < 4; ++nf) { o[nf][0] = 0.f; o[nf][1] = 0.f; o[nf][2] = 0.f; o[nf][3] = 0.f; }

    int jlo = i0 - W1; if (jlo < 0) jlo = 0;
    int jend = i0 + 64 + W1; if (jend > SS) jend = SS;   // exclusive
    int hasCLS = (jlo > 0) ? 1 : 0;
    int nt = hasCLS + (jend - jlo) / 64;
    int iq = i0 + wv * 16 + q15;   // this lane's query row

    for (int tt = 0; tt < nt; ++tt) {
        int base = (hasCLS && tt == 0) ? 0 : jlo + (tt - hasCLS) * 64;
        if (tt > 0) __syncthreads();
        // stage K (swizzled rows)
        #pragma unroll
        for (int op = 0; op < 2; ++op) {
            int r = wv * 16 + op * 8 + (lane >> 3), s = lane & 7;
            gld16(K + (size_t)(b * SS + base + r) * DD + hh * 64 + ((s ^ (r & 7)) * 8),
                  &Ks[(wv * 16 + op * 8) * 64]);
        }
        // stage V transposed: thread handles keys {2k2, 2k2+1}, 8 d's
        {
            int k2 = t & 31, dsec = t >> 5;
            const u16* vp = V + (size_t)(b * SS + base + 2 * k2) * DD + hh * 64 + dsec * 8;
            union { uint4 v; u16 e[8]; } r0, r1;
            r0.v = *(const uint4*)vp;
            r1.v = *(const uint4*)(vp + DD);
            int slot = k2 >> 2;
            #pragma unroll
            for (int j = 0; j < 8; ++j) {
                int d = dsec * 8 + j;
                unsigned val = (unsigned)r0.e[j] | ((unsigned)r1.e[j] << 16);
                *(unsigned*)&Vst[d * 64 + ((slot ^ (d & 7)) * 8) + ((2 * k2) & 7)] = val;
            }
        }
        if (t < 64) msk[t] = (float)mask[b * SS + base + t];
        __syncthreads();

        // S^T = K @ Q^T  (A = K rows, B = Q rows-as-B^T)
        f32x4 sacc[4];
        #pragma unroll
        for (int kf = 0; kf < 4; ++kf) { sacc[kf][0] = 0.f; sacc[kf][1] = 0.f; sacc[kf][2] = 0.f; sacc[kf][3] = 0.f; }
        #pragma unroll
        for (int ks = 0; ks < 2; ++ks) {
            #pragma unroll
            for (int kf = 0; kf < 4; ++kf) {
                int krow = kf * 16 + q15;
                short8 afr = *(const short8*)&Ks[krow * 64 + (((ks * 4 + h) ^ (krow & 7)) * 8)];
                sacc[kf] = __builtin_amdgcn_mfma_f32_16x16x32_bf16(afr, bq[ks], sacc[kf], 0, 0, 0);
            }
        }
        // mask + scale + online softmax (row = query = q15)
        float pv[4][4];
        float tmax = -3e38f;
        #pragma unroll
        for (int kf = 0; kf < 4; ++kf) {
            #pragma unroll
            for (int rg = 0; rg < 4; ++rg) {
                int kl = kf * 16 + h * 4 + rg;
                int key = base + kl;
                int dj = iq - key; int adj = dj < 0 ? -dj : dj;
                bool valid = ((adj <= W1) || (key == 0)) && (msk[kl] != 0.f);
                float s = valid ? sacc[kf][rg] * SCALE : NEGV;
                pv[kf][rg] = s;
                tmax = fmaxf(tmax, s);
            }
        }
        tmax = fmaxf(tmax, __shfl_xor(tmax, 16));
        tmax = fmaxf(tmax, __shfl_xor(tmax, 32));
        float mnew = fmaxf(mrun, tmax);
        float fac = __expf(mrun - mnew);
        mrun = mnew;
        float psum = 0.f;
        #pragma unroll
        for (int kf = 0; kf < 4; ++kf)
            #pragma unroll
            for (int rg = 0; rg < 4; ++rg) {
                float p = __expf(pv[kf][rg] - mnew);
                pv[kf][rg] = p; psum += p;
            }
        psum += __shfl_xor(psum, 16);
        psum += __shfl_xor(psum, 32);
        lrun = lrun * fac + psum;
        // write P row-major [q][key] into per-wave swizzled LDS
        #pragma unroll
        for (int kf = 0; kf < 4; ++kf) {
            unsigned lo = (unsigned)f2bf(pv[kf][0]) | ((unsigned)f2bf(pv[kf][1]) << 16);
            unsigned hi = (unsigned)f2bf(pv[kf][2]) | ((unsigned)f2bf(pv[kf][3]) << 16);
            int slot = 2 * kf + (h >> 1);
            uint2 w; w.x = lo; w.y = hi;
            *(uint2*)&Pld[wv][q15 * 64 + ((slot ^ (q15 & 7)) * 8) + 4 * (h & 1)] = w;
        }
        // rescale O (O-frag rows are q = 4h+rg -> broadcast fac from lane q)
        float fo0 = __shfl(fac, (h * 4 + 0) | (lane & 48));
        float fo1 = __shfl(fac, (h * 4 + 1) | (lane & 48));
        float fo2 = __shfl(fac, (h * 4 + 2) | (lane & 48));
        float fo3 = __shfl(fac, (h * 4 + 3) | (lane & 48));
        #pragma unroll
        for (int nf = 0; nf < 4; ++nf) {
            o[nf][0] *= fo0; o[nf][1] *= fo1; o[nf][2] *= fo2; o[nf][3] *= fo3;
        }
        asm volatile("s_waitcnt lgkmcnt(0)" ::: "memory");   // P-writes visible to own reads
        // O += P @ V
        #pragma unroll
        for (int ks = 0; ks < 2; ++ks) {
            short8 ap = *(const short8*)&Pld[wv][q15 * 64 + (((ks * 4 + h) ^ (q15 & 7)) * 8)];
            #pragma unroll
            for (int nf = 0; nf < 4; ++nf) {
                int d = nf * 16 + q15;
                short8 bvf = *(const short8*)&Vst[d * 64 + (((ks * 4 + h) ^ (d & 7)) * 8)];
                o[nf] = __builtin_amdgcn_mfma_f32_16x16x32_bf16(ap, bvf, o[nf], 0, 0, 0);
            }
        }
    }
    // finalize
    float linv = 1.f / lrun;
    float g0 = __shfl(linv, (h * 4 + 0) | (lane & 48));
    float g1 = __shfl(linv, (h * 4 + 1) | (lane & 48));
    float g2 = __shfl(linv, (h * 4 + 2) | (lane & 48));
    float g3 = __shfl(linv, (h * 4 + 3) | (lane & 48));
    size_t rb = (size_t)(b * SS + i0 + wv * 16 + h * 4);
    #pragma unroll
    for (int nf = 0; nf < 4; ++nf) {
        int d = hh * 64 + nf * 16 + q15;
        AO[(rb + 0) * DD + d] = f2bf(o[nf][0] * g0);
        AO[(rb + 1) * DD + d] = f2bf(o[nf][1] * g1);
        AO[(rb + 2) * DD + d] = f2bf(o[nf][2] * g2);
        AO[(rb + 3) * DD + d] = f2bf(o[nf][3] * g3);
    }
}

// ---------------- tiny GEMV for global query: QG[b,:] = X[b,0,:] @ Wqg + bqg ----------------
__global__ __launch_bounds__(256) void qg_kernel(
    const float* __restrict__ X, const float* __restrict__ W,
    const float* __restrict__ bias, float* __restrict__ QG) {
    int b = blockIdx.x / 3;
    int n = (blockIdx.x % 3) * 256 + threadIdx.x;
    const float* xr = X + (size_t)b * SS * DD;
    float acc = bias[n];
    #pragma unroll 4
    for (int k = 0; k < DD; ++k) acc += xr[k] * W[(size_t)k * DD + n];
    QG[(size_t)b * DD + n] = acc;
}

// ---------------- global (CLS) attention: overwrites AO row 0 (bf16 K/V) ----------------
__global__ __launch_bounds__(256) void attn_global_kernel(
    const float* __restrict__ QG, const u16* __restrict__ KG,
    const u16* __restrict__ VG, const int* __restrict__ mask,
    u16* __restrict__ AO) {
    __shared__ float qv[64];
    __shared__ float sc[SS];
    __shared__ float red[256];
    __shared__ float part[4][64];
    int b = blockIdx.x / HH, hh = blockIdx.x % HH;
    int t = threadIdx.x;
    if (t < 64) qv[t] = QG[(size_t)b * DD + hh * 64 + t];
    __syncthreads();
    for (int j = t; j < SS; j += 256) {
        const u16* kp = KG + (size_t)(b * SS + j) * DD + hh * 64;
        float acc = 0.f;
        #pragma unroll
        for (int d0 = 0; d0 < 64; d0 += 8) {
            union { uint4 v; u16 e[8]; } u;
            u.v = *(const uint4*)(kp + d0);
            #pragma unroll
            for (int j2 = 0; j2 < 8; ++j2) acc += qv[d0 + j2] * bf2f(u.e[j2]);
        }
        sc[j] = mask[b * SS + j] ? acc * SCALE : NEGV;
    }
    __syncthreads();
    float mx = -1e30f;
    for (int j = t; j < SS; j += 256) mx = fmaxf(mx, sc[j]);
    mx = block_reduce_max(mx, red);
    float lsum = 0.f;
    for (int j = t; j < SS; j += 256) {
        float e = __expf(sc[j] - mx);
        sc[j] = e; lsum += e;
    }
    lsum = block_reduce_sum(lsum, red);
    int g = t >> 6, d = t & 63;
    float acc = 0.f;
    for (int j = g; j < SS; j += 4)
        acc += sc[j] * bf2f(VG[(size_t)(b * SS + j) * DD + hh * 64 + d]);
    part[g][d] = acc;
    __syncthreads();
    if (g == 0) {
        float ov = (part[0][d] + part[1][d] + part[2][d] + part[3][d]) / lsum;
        AO[(size_t)(b * SS) * DD + hh * 64 + d] = f2bf(ov);
    }
}

// ---------------- classification head (f32) ----------------
__global__ __launch_bounds__(256) void head_kernel(
    const float* __restrict__ X, const float* __restrict__ motif,
    const float* __restrict__ Wd, const float* __restrict__ bd,
    const float* __restrict__ Wp, const float* __restrict__ bp,
    float* __restrict__ out) {
    __shared__ float hc[HCAT];
    __shared__ float dv[DD];
    __shared__ float red[256];
    int b = blockIdx.x;
    int t = threadIdx.x;
    for (int i = t; i < DD; i += 256) hc[i] = X[(size_t)b * SS * DD + i];
    for (int i = t; i < MOTIF; i += 256) hc[DD + i] = motif[(size_t)b * MOTIF + i];
    __syncthreads();
    for (int j = t; j < DD; j += 256) {
        float acc = bd[j];
        for (int k = 0; k < HCAT; ++k) acc += hc[k] * Wd[(size_t)k * DD + j];
        dv[j] = tanhf(acc);
    }
    __syncthreads();
    float a0 = 0.f, a1 = 0.f;
    for (int k = t; k < DD; k += 256) {
        a0 += dv[k] * Wp[k * 2 + 0];
        a1 += dv[k] * Wp[k * 2 + 1];
    }
    a0 = block_reduce_sum(a0, red);
    a1 = block_reduce_sum(a1, red);
    if (t == 0) {
        out[b * 2 + 0] = a0 + bp[0];
        out[b * 2 + 1] = a1 + bp[1];
    }
}

// ---------------- host launch ----------------
extern "C" void kernel_launch(void* const* d_in, const int* in_sizes, int n_in,
                              void* d_out, int out_size, void* d_ws, size_t ws_size,
                              hipStream_t stream) {
    const int*   input_ids = (const int*)d_in[0];
    const int*   attn_mask = (const int*)d_in[1];
    const float* motif     = (const float*)d_in[2];
    const float* emb_word  = (const float*)d_in[3];
    const float* emb_pos   = (const float*)d_in[4];
    const float* emb_type  = (const float*)d_in[5];
    const float* emb_ln_s  = (const float*)d_in[6];
    const float* emb_ln_b  = (const float*)d_in[7];
    const float* Wq  = (const float*)d_in[8];
    const float* bq  = (const float*)d_in[9];
    const float* Wk  = (const float*)d_in[10];
    const float* bk  = (const float*)d_in[11];
    const float* Wv  = (const float*)d_in[12];
    const float* bv  = (const float*)d_in[13];
    const float* Wqg = (const float*)d_in[14];
    const float* bqg = (const float*)d_in[15];
    const float* Wkg = (const float*)d_in[16];
    const float* bkg = (const float*)d_in[17];
    const float* Wvg = (const float*)d_in[18];
    const float* bvg = (const float*)d_in[19];
    const float* Wo  = (const float*)d_in[20];
    const float* bo  = (const float*)d_in[21];
    const float* ln1_s = (const float*)d_in[22];
    const float* ln1_b = (const float*)d_in[23];
    const float* Wi  = (const float*)d_in[24];
    const float* bi  = (const float*)d_in[25];
    const float* Wo2 = (const float*)d_in[26];
    const float* bo2 = (const float*)d_in[27];
    const float* ln2_s = (const float*)d_in[28];
    const float* ln2_b = (const float*)d_in[29];
    const float* head_Wd = (const float*)d_in[30];
    const float* head_bd = (const float*)d_in[31];
    const float* head_Wp = (const float*)d_in[32];
    const float* head_bp = (const float*)d_in[33];

    float* out = (float*)d_out;
    char* base = (char*)d_ws;

    // byte offsets (B*S*D f32 = 6291456 B; bf16 = 3145728 B)
    float* Xf   = (float*)(base + 0);
    u16*   Xb   = (u16*)  (base + 6291456);
    u16*   Qb   = (u16*)  (base + 9437184);
    u16*   Kb   = (u16*)  (base + 12582912);
    u16*   Vb   = (u16*)  (base + 15728640);
    u16*   KGb  = (u16*)  (base + 18874368);
    u16*   VGb  = (u16*)  (base + 22020096);
    u16*   AOb  = (u16*)  (base + 25165824);
    float* T1f  = (float*)(base + 28311552);
    float* QGf  = (float*)(base + 34603008);
    u16*   Wt6  = (u16*)  (base + 34609152);   // 6 x 768x768 bf16
    u16*   Wti  = (u16*)  (base + 41687040);   // 3072x768 bf16
    u16*   Wto2 = (u16*)  (base + 46405632);   // 768x3072 bf16
    u16*   Hb   = Qb;                          // alias: FF intermediate [2048,3072] over Qb..KGb

    const int nrow = BB * SS;   // 2048
    embed_ln_kernel<<<nrow, 256, 0, stream>>>(input_ids, emb_word, emb_pos, emb_type,
                                              emb_ln_s, emb_ln_b, Xf, Xb);

    dim3 g768(6, 16);    // N=768 tiles
    dim3 gFF(24, 16);    // N=3072 tiles

    for (int l = 0; l < LL; ++l) {
        size_t oDD = (size_t)l * DD * DD;
        conv6_kernel<<<dim3(24, 24, 6), 256, 0, stream>>>(
            Wq + oDD, Wk + oDD, Wv + oDD, Wkg + oDD, Wvg + oDD, Wo + oDD, Wt6);
        convw_t<<<dim3(96, 24), 256, 0, stream>>>(Wi + (size_t)l * DD * FFF, Wti, DD, FFF);
        convw_t<<<dim3(24, 96), 256, 0, stream>>>(Wo2 + (size_t)l * FFF * DD, Wto2, FFF, DD);

        gemm_bf16<0, 1><<<g768, 256, 0, stream>>>(Xb, Wt6 + 0 * (size_t)DD * DD, bq  + l * DD, Qb,  nrow, DD, DD);
        gemm_bf16<0, 1><<<g768, 256, 0, stream>>>(Xb, Wt6 + 1 * (size_t)DD * DD, bk  + l * DD, Kb,  nrow, DD, DD);
        gemm_bf16<0, 1><<<g768, 256, 0, stream>>>(Xb, Wt6 + 2 * (size_t)DD * DD, bv  + l * DD, Vb,  nrow, DD, DD);
        gemm_bf16<0, 1><<<g768, 256, 0, stream>>>(Xb, Wt6 + 3 * (size_t)DD * DD, bkg + l * DD, KGb, nrow, DD, DD);
        gemm_bf16<0, 1><<<g768, 256, 0, stream>>>(Xb, Wt6 + 4 * (size_t)DD * DD, bvg + l * DD, VGb, nrow, DD, DD);
        qg_kernel<<<BB * 3, 256, 0, stream>>>(Xf, Wqg + oDD, bqg + l * DD, QGf);

        attn_local_mfma<<<BB * HH * 16, 256, 0, stream>>>(Qb, Kb, Vb, attn_mask, AOb);
        attn_global_kernel<<<BB * HH, 256, 0, stream>>>(QGf, KGb, VGb, attn_mask, AOb);

        gemm_bf16<0, 0><<<g768, 256, 0, stream>>>(AOb, Wt6 + 5 * (size_t)DD * DD, bo + l * DD, T1f, nrow, DD, DD);
        add_ln_kernel<<<nrow, 256, 0, stream>>>(Xf, Xb, T1f, ln1_s + l * DD, ln1_b + l * DD);

        gemm_bf16<1, 1><<<gFF, 256, 0, stream>>>(Xb, Wti, bi + l * FFF, Hb, nrow, FFF, DD);
        gemm_bf16<0, 0><<<g768, 256, 0, stream>>>(Hb, Wto2, bo2 + l * DD, T1f, nrow, DD, FFF);
        add_ln_kernel<<<nrow, 256, 0, stream>>>(Xf, Xb, T1f, ln2_s + l * DD, ln2_b + l * DD);
    }

    head_kernel<<<BB, 256, 0, stream>>>(Xf, motif, head_Wd, head_bd, head_Wp, head_bp, out);
}

// Round 3
// 5516.661 us; speedup vs baseline: 3.1924x; 1.0007x over previous
//
#include <hip/hip_runtime.h>
#include <math.h>

typedef unsigned short u16;
typedef __attribute__((ext_vector_type(8))) short short8;   // 8 bf16 (4 VGPRs)
typedef __attribute__((ext_vector_type(4))) float f32x4;

#define BB 2
#define SS 1024
#define LL 12
#define HH 12
#define DD 768
#define FFF 3072
#define MOTIF 414
#define HCAT (DD + MOTIF)
#define W1 256
#define NEGV -1e9f
#define EPS 1e-5f
#define SCALE 0.125f

// ---------- bf16 helpers ----------
__device__ __forceinline__ float bf2f(u16 u) {
    union { unsigned i; float f; } x; x.i = ((unsigned)u) << 16; return x.f;
}
__device__ __forceinline__ u16 f2bf(float f) {
    union { float f; unsigned i; } x; x.f = f;
    unsigned r = x.i + 0x7fffu + ((x.i >> 16) & 1u);   // RNE
    return (u16)(r >> 16);
}

// async global->LDS, 16B per lane; lds dest must be wave-uniform base
__device__ __forceinline__ void gld16(const u16* g, u16* l) {
    __builtin_amdgcn_global_load_lds((const __attribute__((address_space(1))) void*)g,
                                     (__attribute__((address_space(3))) void*)l, 16, 0, 0);
}

// ---------------- block reduction helpers (blockDim.x == 256) ----------------
__device__ __forceinline__ float block_reduce_sum(float v, float* red) {
    int t = threadIdx.x;
    red[t] = v; __syncthreads();
    #pragma unroll
    for (int s = 128; s > 0; s >>= 1) {
        if (t < s) red[t] += red[t + s];
        __syncthreads();
    }
    float r = red[0]; __syncthreads();
    return r;
}
__device__ __forceinline__ float block_reduce_max(float v, float* red) {
    int t = threadIdx.x;
    red[t] = v; __syncthreads();
    #pragma unroll
    for (int s = 128; s > 0; s >>= 1) {
        if (t < s) red[t] = fmaxf(red[t], red[t + s]);
        __syncthreads();
    }
    float r = red[0]; __syncthreads();
    return r;
}

// ---------------- embedding + LN (writes f32 X and bf16 Xb) ----------------
__global__ __launch_bounds__(256) void embed_ln_kernel(
    const int* __restrict__ ids, const float* __restrict__ ew,
    const float* __restrict__ ep, const float* __restrict__ et,
    const float* __restrict__ gs, const float* __restrict__ gb,
    float* __restrict__ X, u16* __restrict__ Xb) {
    __shared__ float red[256];
    int row = blockIdx.x;
    int s = row % SS;
    int id = ids[row];
    int t = threadIdx.x;
    float v[3];
    float sum = 0.f;
    #pragma unroll
    for (int i = 0; i < 3; ++i) {
        int d = t + 256 * i;
        float x = ew[(size_t)id * DD + d] + ep[(size_t)(s + 2) * DD + d] + et[d];
        v[i] = x; sum += x;
    }
    sum = block_reduce_sum(sum, red);
    float m = sum * (1.f / DD);
    float sq = 0.f;
    #pragma unroll
    for (int i = 0; i < 3; ++i) { float c = v[i] - m; sq += c * c; }
    sq = block_reduce_sum(sq, red);
    float inv = rsqrtf(sq * (1.f / DD) + EPS);
    #pragma unroll
    for (int i = 0; i < 3; ++i) {
        int d = t + 256 * i;
        float o = (v[i] - m) * inv * gs[d] + gb[d];
        X[(size_t)row * DD + d] = o;
        Xb[(size_t)row * DD + d] = f2bf(o);
    }
}

// ---------------- residual add + LN: X = LN(X + T); also writes bf16 ----------------
__global__ __launch_bounds__(256) void add_ln_kernel(
    float* __restrict__ X, u16* __restrict__ Xb, const float* __restrict__ T,
    const float* __restrict__ gs, const float* __restrict__ gb) {
    __shared__ float red[256];
    int row = blockIdx.x;
    int t = threadIdx.x;
    float v[3];
    float sum = 0.f;
    #pragma unroll
    for (int i = 0; i < 3; ++i) {
        int d = t + 256 * i;
        float x = X[(size_t)row * DD + d] + T[(size_t)row * DD + d];
        v[i] = x; sum += x;
    }
    sum = block_reduce_sum(sum, red);
    float m = sum * (1.f / DD);
    float sq = 0.f;
    #pragma unroll
    for (int i = 0; i < 3; ++i) { float c = v[i] - m; sq += c * c; }
    sq = block_reduce_sum(sq, red);
    float inv = rsqrtf(sq * (1.f / DD) + EPS);
    #pragma unroll
    for (int i = 0; i < 3; ++i) {
        int d = t + 256 * i;
        float o = (v[i] - m) * inv * gs[d] + gb[d];
        X[(size_t)row * DD + d] = o;
        Xb[(size_t)row * DD + d] = f2bf(o);
    }
}

// ---------------- weight convert+transpose: W f32 [K,N] -> Wt bf16 [N,K] ----------------
__global__ __launch_bounds__(256) void convw_t(
    const float* __restrict__ W, u16* __restrict__ Wt, int Kd, int Nd) {
    __shared__ float Tt[32][33];
    int n0 = blockIdx.x * 32, k0 = blockIdx.y * 32;
    int t = threadIdx.x;
    int r = t >> 3, c = (t & 7) * 4;
    float4 v = *(const float4*)(W + (size_t)(k0 + r) * Nd + n0 + c);
    Tt[r][c] = v.x; Tt[r][c + 1] = v.y; Tt[r][c + 2] = v.z; Tt[r][c + 3] = v.w;
    __syncthreads();
    int n = t >> 3, k4 = (t & 7) * 4;
    unsigned lo = (unsigned)f2bf(Tt[k4][n])     | ((unsigned)f2bf(Tt[k4 + 1][n]) << 16);
    unsigned hi = (unsigned)f2bf(Tt[k4 + 2][n]) | ((unsigned)f2bf(Tt[k4 + 3][n]) << 16);
    uint2 wv; wv.x = lo; wv.y = hi;
    *(uint2*)&Wt[(size_t)(n0 + n) * Kd + k0 + k4] = wv;
}

// six 768x768 weights in one launch (z selects matrix)
__global__ __launch_bounds__(256) void conv6_kernel(
    const float* w0, const float* w1, const float* w2,
    const float* w3, const float* w4, const float* w5, u16* __restrict__ outb) {
    __shared__ float Tt[32][33];
    int z = blockIdx.z;
    const float* W = (z == 0) ? w0 : (z == 1) ? w1 : (z == 2) ? w2 : (z == 3) ? w3 : (z == 4) ? w4 : w5;
    u16* Wt = outb + (size_t)z * DD * DD;
    int n0 = blockIdx.x * 32, k0 = blockIdx.y * 32;
    int t = threadIdx.x;
    int r = t >> 3, c = (t & 7) * 4;
    float4 v = *(const float4*)(W + (size_t)(k0 + r) * DD + n0 + c);
    Tt[r][c] = v.x; Tt[r][c + 1] = v.y; Tt[r][c + 2] = v.z; Tt[r][c + 3] = v.w;
    __syncthreads();
    int n = t >> 3, k4 = (t & 7) * 4;
    unsigned lo = (unsigned)f2bf(Tt[k4][n])     | ((unsigned)f2bf(Tt[k4 + 1][n]) << 16);
    unsigned hi = (unsigned)f2bf(Tt[k4 + 2][n]) | ((unsigned)f2bf(Tt[k4 + 3][n]) << 16);
    uint2 wv; wv.x = lo; wv.y = hi;
    *(uint2*)&Wt[(size_t)(n0 + n) * DD + k0 + k4] = wv;
}

// ---------------- bf16 MFMA GEMM: C[M,N] = A[M,K] @ Wt[N,K]^T + bias ----------------
// ACT: 0 none, 1 exact gelu.  OBF: 1 -> bf16 out, 0 -> f32 out.
template <int ACT, int OBF>
__global__ __launch_bounds__(256) void gemm_bf16(
    const u16* __restrict__ A, const u16* __restrict__ Bt,
    const float* __restrict__ bias, void* __restrict__ Cout,
    int M, int N, int K) {
    __shared__ __align__(16) u16 As[128 * 32];
    __shared__ __align__(16) u16 Bs[128 * 32];
    int t = threadIdx.x, lane = t & 63, wv = t >> 6;
    int bm = blockIdx.y * 128, bn = blockIdx.x * 128;
    int wm = wv >> 1, wn = wv & 1;
    int h = lane >> 4, q15 = lane & 15;
    f32x4 acc[4][4];
    #pragma unroll
    for (int i = 0; i < 4; ++i)
        #pragma unroll
        for (int j = 0; j < 4; ++j) { acc[i][j][0] = 0.f; acc[i][j][1] = 0.f; acc[i][j][2] = 0.f; acc[i][j][3] = 0.f; }

    for (int k0 = 0; k0 < K; k0 += 32) {
        #pragma unroll
        for (int op = 0; op < 2; ++op) {
            int rc = wv * 32 + op * 16;
            int r = rc + (lane >> 2), s = lane & 3;
            gld16(A  + (size_t)(bm + r) * K + k0 + ((s ^ (r & 3)) * 8), &As[rc * 32]);
            gld16(Bt + (size_t)(bn + r) * K + k0 + ((s ^ (r & 3)) * 8), &Bs[rc * 32]);
        }
        __syncthreads();
        short8 af[4], bfr[4];
        #pragma unroll
        for (int mf = 0; mf < 4; ++mf) {
            int row = wm * 64 + mf * 16 + q15;
            af[mf] = *(const short8*)&As[row * 32 + ((h ^ (row & 3)) * 8)];
        }
        #pragma unroll
        for (int nf = 0; nf < 4; ++nf) {
            int row = wn * 64 + nf * 16 + q15;
            bfr[nf] = *(const short8*)&Bs[row * 32 + ((h ^ (row & 3)) * 8)];
        }
        #pragma unroll
        for (int mf = 0; mf < 4; ++mf)
            #pragma unroll
            for (int nf = 0; nf < 4; ++nf)
                acc[mf][nf] = __builtin_amdgcn_mfma_f32_16x16x32_bf16(af[mf], bfr[nf], acc[mf][nf], 0, 0, 0);
        __syncthreads();
    }
    float* Cf = (float*)Cout;
    u16*   Cb = (u16*)Cout;
    #pragma unroll
    for (int mf = 0; mf < 4; ++mf) {
        int mbase = bm + wm * 64 + mf * 16 + h * 4;
        #pragma unroll
        for (int nf = 0; nf < 4; ++nf) {
            int n = bn + wn * 64 + nf * 16 + q15;
            float bv = bias[n];
            #pragma unroll
            for (int rg = 0; rg < 4; ++rg) {
                float val = acc[mf][nf][rg] + bv;
                if (ACT == 1) val = 0.5f * val * (1.f + erff(val * 0.70710678118654752f));
                if (OBF) Cb[(size_t)(mbase + rg) * N + n] = f2bf(val);
                else     Cf[(size_t)(mbase + rg) * N + n] = val;
            }
        }
    }
}

// ---------------- fused local-window flash attention (MFMA) ----------------
// one block per (b, h, 64-query tile); Q,K,V bf16 row-major [B*S][768]
__global__ __launch_bounds__(256) void attn_local_mfma(
    const u16* __restrict__ Q, const u16* __restrict__ K,
    const u16* __restrict__ V, const int* __restrict__ mask,
    u16* __restrict__ AO) {
    __shared__ __align__(16) u16 Qs[64 * 64];
    __shared__ __align__(16) u16 Ks[64 * 64];
    __shared__ __align__(16) u16 Vst[64 * 64];   // transposed: [d][key], swizzled
    __shared__ __align__(16) u16 Pld[4][16 * 64];
    __shared__ float msk[64];
    int bid = blockIdx.x;
    int qt = bid & 15;
    int hh = (bid >> 4) % HH;
    int b  = bid / (16 * HH);
    int t = threadIdx.x, lane = t & 63, wv = t >> 6;
    int h = lane >> 4, q15 = lane & 15;
    int i0 = qt * 64;

    // stage Q (swizzled source, linear LDS dest)
    #pragma unroll
    for (int op = 0; op < 2; ++op) {
        int r = wv * 16 + op * 8 + (lane >> 3), s = lane & 7;
        gld16(Q + (size_t)(b * SS + i0 + r) * DD + hh * 64 + ((s ^ (r & 7)) * 8),
              &Qs[(wv * 16 + op * 8) * 64]);
    }
    __syncthreads();
    // hoist Q B-fragments (per-wave rows)
    short8 bq[2];
    {
        int qrow = wv * 16 + q15;
        #pragma unroll
        for (int ks = 0; ks < 2; ++ks)
            bq[ks] = *(const short8*)&Qs[qrow * 64 + (((ks * 4 + h) ^ (qrow & 7)) * 8)];
    }

    float mrun = -3e38f, lrun = 0.f;
    f32x4 o[4];
    #pragma unroll
    for (int nf = 0; nf < 4; ++nf) { o[nf][0] = 0.f; o[nf][1] = 0.f; o[nf][2] = 0.f; o[nf][3] = 0.f; }

    int jlo = i0 - W1; if (jlo < 0) jlo = 0;
    int jend = i0 + 64 + W1; if (jend > SS) jend = SS;   // exclusive
    int hasCLS = (jlo > 0) ? 1 : 0;
    int nt = hasCLS + (jend - jlo) / 64;
    int iq = i0 + wv * 16 + q15;   // this lane's query row

    for (int tt = 0; tt < nt; ++tt) {
        int base = (hasCLS && tt == 0) ? 0 : jlo + (tt - hasCLS) * 64;
        if (tt > 0) __syncthreads();
        // stage K (swizzled rows)
        #pragma unroll
        for (int op = 0; op < 2; ++op) {
            int r = wv * 16 + op * 8 + (lane >> 3), s = lane & 7;
            gld16(K + (size_t)(b * SS + base + r) * DD + hh * 64 + ((s ^ (r & 7)) * 8),
                  &Ks[(wv * 16 + op * 8) * 64]);
        }
        // stage V transposed: thread handles keys {2k2, 2k2+1}, 8 d's
        {
            int k2 = t & 31, dsec = t >> 5;
            const u16* vp = V + (size_t)(b * SS + base + 2 * k2) * DD + hh * 64 + dsec * 8;
            union { uint4 v; u16 e[8]; } r0, r1;
            r0.v = *(const uint4*)vp;
            r1.v = *(const uint4*)(vp + DD);
            int slot = k2 >> 2;
            #pragma unroll
            for (int j = 0; j < 8; ++j) {
                int d = dsec * 8 + j;
                unsigned val = (unsigned)r0.e[j] | ((unsigned)r1.e[j] << 16);
                *(unsigned*)&Vst[d * 64 + ((slot ^ (d & 7)) * 8) + ((2 * k2) & 7)] = val;
            }
        }
        if (t < 64) msk[t] = (float)mask[b * SS + base + t];
        __syncthreads();

        // S^T = K @ Q^T  (A = K rows, B = Q rows-as-B^T)
        f32x4 sacc[4];
        #pragma unroll
        for (int kf = 0; kf < 4; ++kf) { sacc[kf][0] = 0.f; sacc[kf][1] = 0.f; sacc[kf][2] = 0.f; sacc[kf][3] = 0.f; }
        #pragma unroll
        for (int ks = 0; ks < 2; ++ks) {
            #pragma unroll
            for (int kf = 0; kf < 4; ++kf) {
                int krow = kf * 16 + q15;
                short8 afr = *(const short8*)&Ks[krow * 64 + (((ks * 4 + h) ^ (krow & 7)) * 8)];
                sacc[kf] = __builtin_amdgcn_mfma_f32_16x16x32_bf16(afr, bq[ks], sacc[kf], 0, 0, 0);
            }
        }
        // mask + scale + online softmax (row = query = q15)
        float pv[4][4];
        float tmax = -3e38f;
        #pragma unroll
        for (int kf = 0; kf < 4; ++kf) {
            #pragma unroll
            for (int rg = 0; rg < 4; ++rg) {
                int kl = kf * 16 + h * 4 + rg;
                int key = base + kl;
                int dj = iq - key; int adj = dj < 0 ? -dj : dj;
                bool valid = ((adj <= W1) || (key == 0)) && (msk[kl] != 0.f);
                float s = valid ? sacc[kf][rg] * SCALE : NEGV;
                pv[kf][rg] = s;
                tmax = fmaxf(tmax, s);
            }
        }
        tmax = fmaxf(tmax, __shfl_xor(tmax, 16));
        tmax = fmaxf(tmax, __shfl_xor(tmax, 32));
        float mnew = fmaxf(mrun, tmax);
        float fac = __expf(mrun - mnew);
        mrun = mnew;
        float psum = 0.f;
        #pragma unroll
        for (int kf = 0; kf < 4; ++kf)
            #pragma unroll
            for (int rg = 0; rg < 4; ++rg) {
                float p = __expf(pv[kf][rg] - mnew);
                pv[kf][rg] = p; psum += p;
            }
        psum += __shfl_xor(psum, 16);
        psum += __shfl_xor(psum, 32);
        lrun = lrun * fac + psum;
        // write P row-major [q][key] into per-wave swizzled LDS
        #pragma unroll
        for (int kf = 0; kf < 4; ++kf) {
            unsigned lo = (unsigned)f2bf(pv[kf][0]) | ((unsigned)f2bf(pv[kf][1]) << 16);
            unsigned hi = (unsigned)f2bf(pv[kf][2]) | ((unsigned)f2bf(pv[kf][3]) << 16);
            int slot = 2 * kf + (h >> 1);
            uint2 w; w.x = lo; w.y = hi;
            *(uint2*)&Pld[wv][q15 * 64 + ((slot ^ (q15 & 7)) * 8) + 4 * (h & 1)] = w;
        }
        // rescale O (O-frag rows are q = 4h+rg -> broadcast fac from lane q)
        float fo0 = __shfl(fac, (h * 4 + 0) | (lane & 48));
        float fo1 = __shfl(fac, (h * 4 + 1) | (lane & 48));
        float fo2 = __shfl(fac, (h * 4 + 2) | (lane & 48));
        float fo3 = __shfl(fac, (h * 4 + 3) | (lane & 48));
        #pragma unroll
        for (int nf = 0; nf < 4; ++nf) {
            o[nf][0] *= fo0; o[nf][1] *= fo1; o[nf][2] *= fo2; o[nf][3] *= fo3;
        }
        asm volatile("s_waitcnt lgkmcnt(0)" ::: "memory");   // P-writes visible to own reads
        // O += P @ V
        #pragma unroll
        for (int ks = 0; ks < 2; ++ks) {
            short8 ap = *(const short8*)&Pld[wv][q15 * 64 + (((ks * 4 + h) ^ (q15 & 7)) * 8)];
            #pragma unroll
            for (int nf = 0; nf < 4; ++nf) {
                int d = nf * 16 + q15;
                short8 bvf = *(const short8*)&Vst[d * 64 + (((ks * 4 + h) ^ (d & 7)) * 8)];
                o[nf] = __builtin_amdgcn_mfma_f32_16x16x32_bf16(ap, bvf, o[nf], 0, 0, 0);
            }
        }
    }
    // finalize
    float linv = 1.f / lrun;
    float g0 = __shfl(linv, (h * 4 + 0) | (lane & 48));
    float g1 = __shfl(linv, (h * 4 + 1) | (lane & 48));
    float g2 = __shfl(linv, (h * 4 + 2) | (lane & 48));
    float g3 = __shfl(linv, (h * 4 + 3) | (lane & 48));
    size_t rb = (size_t)(b * SS + i0 + wv * 16 + h * 4);
    #pragma unroll
    for (int nf = 0; nf < 4; ++nf) {
        int d = hh * 64 + nf * 16 + q15;
        AO[(rb + 0) * DD + d] = f2bf(o[nf][0] * g0);
        AO[(rb + 1) * DD + d] = f2bf(o[nf][1] * g1);
        AO[(rb + 2) * DD + d] = f2bf(o[nf][2] * g2);
        AO[(rb + 3) * DD + d] = f2bf(o[nf][3] * g3);
    }
}

// ---------------- tiny GEMV for global query: QG[b,:] = X[b,0,:] @ Wqg + bqg ----------------
__global__ __launch_bounds__(256) void qg_kernel(
    const float* __restrict__ X, const float* __restrict__ W,
    const float* __restrict__ bias, float* __restrict__ QG) {
    int b = blockIdx.x / 3;
    int n = (blockIdx.x % 3) * 256 + threadIdx.x;
    const float* xr = X + (size_t)b * SS * DD;
    float acc = bias[n];
    #pragma unroll 4
    for (int k = 0; k < DD; ++k) acc += xr[k] * W[(size_t)k * DD + n];
    QG[(size_t)b * DD + n] = acc;
}

// ---------------- global (CLS) attention: overwrites AO row 0 (bf16 K/V) ----------------
__global__ __launch_bounds__(256) void attn_global_kernel(
    const float* __restrict__ QG, const u16* __restrict__ KG,
    const u16* __restrict__ VG, const int* __restrict__ mask,
    u16* __restrict__ AO) {
    __shared__ float qv[64];
    __shared__ float sc[SS];
    __shared__ float red[256];
    __shared__ float part[4][64];
    int b = blockIdx.x / HH, hh = blockIdx.x % HH;
    int t = threadIdx.x;
    if (t < 64) qv[t] = QG[(size_t)b * DD + hh * 64 + t];
    __syncthreads();
    for (int j = t; j < SS; j += 256) {
        const u16* kp = KG + (size_t)(b * SS + j) * DD + hh * 64;
        float acc = 0.f;
        #pragma unroll
        for (int d0 = 0; d0 < 64; d0 += 8) {
            union { uint4 v; u16 e[8]; } u;
            u.v = *(const uint4*)(kp + d0);
            #pragma unroll
            for (int j2 = 0; j2 < 8; ++j2) acc += qv[d0 + j2] * bf2f(u.e[j2]);
        }
        sc[j] = mask[b * SS + j] ? acc * SCALE : NEGV;
    }
    __syncthreads();
    float mx = -1e30f;
    for (int j = t; j < SS; j += 256) mx = fmaxf(mx, sc[j]);
    mx = block_reduce_max(mx, red);
    float lsum = 0.f;
    for (int j = t; j < SS; j += 256) {
        float e = __expf(sc[j] - mx);
        sc[j] = e; lsum += e;
    }
    lsum = block_reduce_sum(lsum, red);
    int g = t >> 6, d = t & 63;
    float acc = 0.f;
    for (int j = g; j < SS; j += 4)
        acc += sc[j] * bf2f(VG[(size_t)(b * SS + j) * DD + hh * 64 + d]);
    part[g][d] = acc;
    __syncthreads();
    if (g == 0) {
        float ov = (part[0][d] + part[1][d] + part[2][d] + part[3][d]) / lsum;
        AO[(size_t)(b * SS) * DD + hh * 64 + d] = f2bf(ov);
    }
}

// ---------------- classification head (f32) ----------------
__global__ __launch_bounds__(256) void head_kernel(
    const float* __restrict__ X, const float* __restrict__ motif,
    const float* __restrict__ Wd, const float* __restrict__ bd,
    const float* __restrict__ Wp, const float* __restrict__ bp,
    float* __restrict__ out) {
    __shared__ float hc[HCAT];
    __shared__ float dv[DD];
    __shared__ float red[256];
    int b = blockIdx.x;
    int t = threadIdx.x;
    for (int i = t; i < DD; i += 256) hc[i] = X[(size_t)b * SS * DD + i];
    for (int i = t; i < MOTIF; i += 256) hc[DD + i] = motif[(size_t)b * MOTIF + i];
    __syncthreads();
    for (int j = t; j < DD; j += 256) {
        float acc = bd[j];
        for (int k = 0; k < HCAT; ++k) acc += hc[k] * Wd[(size_t)k * DD + j];
        dv[j] = tanhf(acc);
    }
    __syncthreads();
    float a0 = 0.f, a1 = 0.f;
    for (int k = t; k < DD; k += 256) {
        a0 += dv[k] * Wp[k * 2 + 0];
        a1 += dv[k] * Wp[k * 2 + 1];
    }
    a0 = block_reduce_sum(a0, red);
    a1 = block_reduce_sum(a1, red);
    if (t == 0) {
        out[b * 2 + 0] = a0 + bp[0];
        out[b * 2 + 1] = a1 + bp[1];
    }
}

// ---------------- host launch ----------------
extern "C" void kernel_launch(void* const* d_in, const int* in_sizes, int n_in,
                              void* d_out, int out_size, void* d_ws, size_t ws_size,
                              hipStream_t stream) {
    const int*   input_ids = (const int*)d_in[0];
    const int*   attn_mask = (const int*)d_in[1];
    const float* motif     = (const float*)d_in[2];
    const float* emb_word  = (const float*)d_in[3];
    const float* emb_pos   = (const float*)d_in[4];
    const float* emb_type  = (const float*)d_in[5];
    const float* emb_ln_s  = (const float*)d_in[6];
    const float* emb_ln_b  = (const float*)d_in[7];
    const float* Wq  = (const float*)d_in[8];
    const float* bq  = (const float*)d_in[9];
    const float* Wk  = (const float*)d_in[10];
    const float* bk  = (const float*)d_in[11];
    const float* Wv  = (const float*)d_in[12];
    const float* bv  = (const float*)d_in[13];
    const float* Wqg = (const float*)d_in[14];
    const float* bqg = (const float*)d_in[15];
    const float* Wkg = (const float*)d_in[16];
    const float* bkg = (const float*)d_in[17];
    const float* Wvg = (const float*)d_in[18];
    const float* bvg = (const float*)d_in[19];
    const float* Wo  = (const float*)d_in[20];
    const float* bo  = (const float*)d_in[21];
    const float* ln1_s = (const float*)d_in[22];
    const float* ln1_b = (const float*)d_in[23];
    const float* Wi  = (const float*)d_in[24];
    const float* bi  = (const float*)d_in[25];
    const float* Wo2 = (const float*)d_in[26];
    const float* bo2 = (const float*)d_in[27];
    const float* ln2_s = (const float*)d_in[28];
    const float* ln2_b = (const float*)d_in[29];
    const float* head_Wd = (const float*)d_in[30];
    const float* head_bd = (const float*)d_in[31];
    const float* head_Wp = (const float*)d_in[32];
    const float* head_bp = (const float*)d_in[33];

    float* out = (float*)d_out;
    char* base = (char*)d_ws;

    // byte offsets (B*S*D f32 = 6291456 B; bf16 = 3145728 B)
    float* Xf   = (float*)(base + 0);
    u16*   Xb   = (u16*)  (base + 6291456);
    u16*   Qb   = (u16*)  (base + 9437184);
    u16*   Kb   = (u16*)  (base + 12582912);
    u16*   Vb   = (u16*)  (base + 15728640);
    u16*   KGb  = (u16*)  (base + 18874368);
    u16*   VGb  = (u16*)  (base + 22020096);
    u16*   AOb  = (u16*)  (base + 25165824);
    float* T1f  = (float*)(base + 28311552);
    float* QGf  = (float*)(base + 34603008);
    u16*   Wt6  = (u16*)  (base + 34609152);   // 6 x 768x768 bf16
    u16*   Wti  = (u16*)  (base + 41687040);   // 3072x768 bf16
    u16*   Wto2 = (u16*)  (base + 46405632);   // 768x3072 bf16
    u16*   Hb   = Qb;                          // alias: FF intermediate [2048,3072] over Qb..KGb

    const int nrow = BB * SS;   // 2048
    embed_ln_kernel<<<nrow, 256, 0, stream>>>(input_ids, emb_word, emb_pos, emb_type,
                                              emb_ln_s, emb_ln_b, Xf, Xb);

    dim3 g768(6, 16);    // N=768 tiles
    dim3 gFF(24, 16);    // N=3072 tiles

    for (int l = 0; l < LL; ++l) {
        size_t oDD = (size_t)l * DD * DD;
        conv6_kernel<<<dim3(24, 24, 6), 256, 0, stream>>>(
            Wq + oDD, Wk + oDD, Wv + oDD, Wkg + oDD, Wvg + oDD, Wo + oDD, Wt6);
        convw_t<<<dim3(96, 24), 256, 0, stream>>>(Wi + (size_t)l * DD * FFF, Wti, DD, FFF);
        convw_t<<<dim3(24, 96), 256, 0, stream>>>(Wo2 + (size_t)l * FFF * DD, Wto2, FFF, DD);

        gemm_bf16<0, 1><<<g768, 256, 0, stream>>>(Xb, Wt6 + 0 * (size_t)DD * DD, bq  + l * DD, Qb,  nrow, DD, DD);
        gemm_bf16<0, 1><<<g768, 256, 0, stream>>>(Xb, Wt6 + 1 * (size_t)DD * DD, bk  + l * DD, Kb,  nrow, DD, DD);
        gemm_bf16<0, 1><<<g768, 256, 0, stream>>>(Xb, Wt6 + 2 * (size_t)DD * DD, bv  + l * DD, Vb,  nrow, DD, DD);
        gemm_bf16<0, 1><<<g768, 256, 0, stream>>>(Xb, Wt6 + 3 * (size_t)DD * DD, bkg + l * DD, KGb, nrow, DD, DD);
        gemm_bf16<0, 1><<<g768, 256, 0, stream>>>(Xb, Wt6 + 4 * (size_t)DD * DD, bvg + l * DD, VGb, nrow, DD, DD);
        qg_kernel<<<BB * 3, 256, 0, stream>>>(Xf, Wqg + oDD, bqg + l * DD, QGf);

        attn_local_mfma<<<BB * HH * 16, 256, 0, stream>>>(Qb, Kb, Vb, attn_mask, AOb);
        attn_global_kernel<<<BB * HH, 256, 0, stream>>>(QGf, KGb, VGb, attn_mask, AOb);

        gemm_bf16<0, 0><<<g768, 256, 0, stream>>>(AOb, Wt6 + 5 * (size_t)DD * DD, bo + l * DD, T1f, nrow, DD, DD);
        add_ln_kernel<<<nrow, 256, 0, stream>>>(Xf, Xb, T1f, ln1_s + l * DD, ln1_b + l * DD);

        gemm_bf16<1, 1><<<gFF, 256, 0, stream>>>(Xb, Wti, bi + l * FFF, Hb, nrow, FFF, DD);
        gemm_bf16<0, 0><<<g768, 256, 0, stream>>>(Hb, Wto2, bo2 + l * DD, T1f, nrow, DD, FFF);
        add_ln_kernel<<<nrow, 256, 0, stream>>>(Xf, Xb, T1f, ln2_s + l * DD, ln2_b + l * DD);
    }

    head_kernel<<<BB, 256, 0, stream>>>(Xf, motif, head_Wd, head_bd, head_Wp, head_bp, out);
}

// Round 4
// 3745.475 us; speedup vs baseline: 4.7020x; 1.4729x over previous
//
#include <hip/hip_runtime.h>
#include <math.h>

typedef unsigned short u16;
typedef __attribute__((ext_vector_type(8))) short short8;   // 8 bf16 (4 VGPRs)
typedef __attribute__((ext_vector_type(4))) float f32x4;

#define BB 2
#define SS 1024
#define LL 12
#define HH 12
#define DD 768
#define FFF 3072
#define MOTIF 414
#define HCAT (DD + MOTIF)
#define W1 256
#define NEGV -1e9f
#define EPS 1e-5f
#define SCALE 0.125f
#define LD5 3840            // 5*768, QKV buffer row stride

// ---------- bf16 helpers ----------
__device__ __forceinline__ float bf2f(u16 u) {
    union { unsigned i; float f; } x; x.i = ((unsigned)u) << 16; return x.f;
}
__device__ __forceinline__ u16 f2bf(float f) {
    union { float f; unsigned i; } x; x.f = f;
    unsigned r = x.i + 0x7fffu + ((x.i >> 16) & 1u);   // RNE
    return (u16)(r >> 16);
}

// async global->LDS, 16B per lane; lds dest must be wave-uniform base
__device__ __forceinline__ void gld16(const u16* g, u16* l) {
    __builtin_amdgcn_global_load_lds((const __attribute__((address_space(1))) void*)g,
                                     (__attribute__((address_space(3))) void*)l, 16, 0, 0);
}

// ---------------- block reduction helpers (blockDim.x == 256) ----------------
__device__ __forceinline__ float block_reduce_sum(float v, float* red) {
    int t = threadIdx.x;
    red[t] = v; __syncthreads();
    #pragma unroll
    for (int s = 128; s > 0; s >>= 1) {
        if (t < s) red[t] += red[t + s];
        __syncthreads();
    }
    float r = red[0]; __syncthreads();
    return r;
}
__device__ __forceinline__ float block_reduce_max(float v, float* red) {
    int t = threadIdx.x;
    red[t] = v; __syncthreads();
    #pragma unroll
    for (int s = 128; s > 0; s >>= 1) {
        if (t < s) red[t] = fmaxf(red[t], red[t + s]);
        __syncthreads();
    }
    float r = red[0]; __syncthreads();
    return r;
}

// ---------------- embedding + LN (writes f32 X and bf16 Xb) ----------------
__global__ __launch_bounds__(256) void embed_ln_kernel(
    const int* __restrict__ ids, const float* __restrict__ ew,
    const float* __restrict__ ep, const float* __restrict__ et,
    const float* __restrict__ gs, const float* __restrict__ gb,
    float* __restrict__ X, u16* __restrict__ Xb) {
    __shared__ float red[256];
    int row = blockIdx.x;
    int s = row % SS;
    int id = ids[row];
    int t = threadIdx.x;
    float v[3];
    float sum = 0.f;
    #pragma unroll
    for (int i = 0; i < 3; ++i) {
        int d = t + 256 * i;
        float x = ew[(size_t)id * DD + d] + ep[(size_t)(s + 2) * DD + d] + et[d];
        v[i] = x; sum += x;
    }
    sum = block_reduce_sum(sum, red);
    float m = sum * (1.f / DD);
    float sq = 0.f;
    #pragma unroll
    for (int i = 0; i < 3; ++i) { float c = v[i] - m; sq += c * c; }
    sq = block_reduce_sum(sq, red);
    float inv = rsqrtf(sq * (1.f / DD) + EPS);
    #pragma unroll
    for (int i = 0; i < 3; ++i) {
        int d = t + 256 * i;
        float o = (v[i] - m) * inv * gs[d] + gb[d];
        X[(size_t)row * DD + d] = o;
        Xb[(size_t)row * DD + d] = f2bf(o);
    }
}

// ---------------- residual add + LN: X = LN(X + T); also writes bf16 ----------------
__global__ __launch_bounds__(256) void add_ln_kernel(
    float* __restrict__ X, u16* __restrict__ Xb, const float* __restrict__ T,
    const float* __restrict__ gs, const float* __restrict__ gb) {
    __shared__ float red[256];
    int row = blockIdx.x;
    int t = threadIdx.x;
    float v[3];
    float sum = 0.f;
    #pragma unroll
    for (int i = 0; i < 3; ++i) {
        int d = t + 256 * i;
        float x = X[(size_t)row * DD + d] + T[(size_t)row * DD + d];
        v[i] = x; sum += x;
    }
    sum = block_reduce_sum(sum, red);
    float m = sum * (1.f / DD);
    float sq = 0.f;
    #pragma unroll
    for (int i = 0; i < 3; ++i) { float c = v[i] - m; sq += c * c; }
    sq = block_reduce_sum(sq, red);
    float inv = rsqrtf(sq * (1.f / DD) + EPS);
    #pragma unroll
    for (int i = 0; i < 3; ++i) {
        int d = t + 256 * i;
        float o = (v[i] - m) * inv * gs[d] + gb[d];
        X[(size_t)row * DD + d] = o;
        Xb[(size_t)row * DD + d] = f2bf(o);
    }
}

// ---------------- weight convert+transpose: W f32 [K,N] -> Wt bf16 [N,K] ----------------
__global__ __launch_bounds__(256) void convw_t(
    const float* __restrict__ W, u16* __restrict__ Wt, int Kd, int Nd) {
    __shared__ float Tt[32][33];
    int n0 = blockIdx.x * 32, k0 = blockIdx.y * 32;
    int t = threadIdx.x;
    int r = t >> 3, c = (t & 7) * 4;
    float4 v = *(const float4*)(W + (size_t)(k0 + r) * Nd + n0 + c);
    Tt[r][c] = v.x; Tt[r][c + 1] = v.y; Tt[r][c + 2] = v.z; Tt[r][c + 3] = v.w;
    __syncthreads();
    int n = t >> 3, k4 = (t & 7) * 4;
    unsigned lo = (unsigned)f2bf(Tt[k4][n])     | ((unsigned)f2bf(Tt[k4 + 1][n]) << 16);
    unsigned hi = (unsigned)f2bf(Tt[k4 + 2][n]) | ((unsigned)f2bf(Tt[k4 + 3][n]) << 16);
    uint2 wv; wv.x = lo; wv.y = hi;
    *(uint2*)&Wt[(size_t)(n0 + n) * Kd + k0 + k4] = wv;
}

// six 768x768 weights in one launch (z selects matrix)
__global__ __launch_bounds__(256) void conv6_kernel(
    const float* w0, const float* w1, const float* w2,
    const float* w3, const float* w4, const float* w5, u16* __restrict__ outb) {
    __shared__ float Tt[32][33];
    int z = blockIdx.z;
    const float* W = (z == 0) ? w0 : (z == 1) ? w1 : (z == 2) ? w2 : (z == 3) ? w3 : (z == 4) ? w4 : w5;
    u16* Wt = outb + (size_t)z * DD * DD;
    int n0 = blockIdx.x * 32, k0 = blockIdx.y * 32;
    int t = threadIdx.x;
    int r = t >> 3, c = (t & 7) * 4;
    float4 v = *(const float4*)(W + (size_t)(k0 + r) * DD + n0 + c);
    Tt[r][c] = v.x; Tt[r][c + 1] = v.y; Tt[r][c + 2] = v.z; Tt[r][c + 3] = v.w;
    __syncthreads();
    int n = t >> 3, k4 = (t & 7) * 4;
    unsigned lo = (unsigned)f2bf(Tt[k4][n])     | ((unsigned)f2bf(Tt[k4 + 1][n]) << 16);
    unsigned hi = (unsigned)f2bf(Tt[k4 + 2][n]) | ((unsigned)f2bf(Tt[k4 + 3][n]) << 16);
    uint2 wv; wv.x = lo; wv.y = hi;
    *(uint2*)&Wt[(size_t)(n0 + n) * DD + k0 + k4] = wv;
}

// ---------------- bias concat for batched QKV gemm: bcat[l][5*768] ----------------
__global__ __launch_bounds__(256) void bcat_kernel(
    const float* __restrict__ bq, const float* __restrict__ bk,
    const float* __restrict__ bv, const float* __restrict__ bkg,
    const float* __restrict__ bvg, float* __restrict__ bcat) {
    int tid = blockIdx.x * 256 + threadIdx.x;
    if (tid >= LL * LD5) return;
    int l = tid / LD5, r = tid % LD5, z = r / DD, j = r % DD;
    const float* src = (z == 0) ? bq : (z == 1) ? bk : (z == 2) ? bv : (z == 3) ? bkg : bvg;
    bcat[tid] = src[l * DD + j];
}

// ---------------- bf16 MFMA GEMM: C[M,N] = A[M,K] @ Bt[N,K]^T + bias ----------------
// ACT: 0 none, 1 exact gelu.  OBF: 1 -> bf16 out, 0 -> f32 out.
template <int ACT, int OBF>
__global__ __launch_bounds__(256) void gemm_bf16(
    const u16* __restrict__ A, const u16* __restrict__ Bt,
    const float* __restrict__ bias, void* __restrict__ Cout,
    int M, int N, int K) {
    __shared__ __align__(16) u16 As[128 * 32];
    __shared__ __align__(16) u16 Bs[128 * 32];
    int t = threadIdx.x, lane = t & 63, wv = t >> 6;
    int bm = blockIdx.y * 128, bn = blockIdx.x * 128;
    int wm = wv >> 1, wn = wv & 1;
    int h = lane >> 4, q15 = lane & 15;
    f32x4 acc[4][4];
    #pragma unroll
    for (int i = 0; i < 4; ++i)
        #pragma unroll
        for (int j = 0; j < 4; ++j) { acc[i][j][0] = 0.f; acc[i][j][1] = 0.f; acc[i][j][2] = 0.f; acc[i][j][3] = 0.f; }

    for (int k0 = 0; k0 < K; k0 += 32) {
        #pragma unroll
        for (int op = 0; op < 2; ++op) {
            int rc = wv * 32 + op * 16;
            int r = rc + (lane >> 2), s = lane & 3;
            gld16(A  + (size_t)(bm + r) * K + k0 + ((s ^ (r & 3)) * 8), &As[rc * 32]);
            gld16(Bt + (size_t)(bn + r) * K + k0 + ((s ^ (r & 3)) * 8), &Bs[rc * 32]);
        }
        __syncthreads();
        short8 af[4], bfr[4];
        #pragma unroll
        for (int mf = 0; mf < 4; ++mf) {
            int row = wm * 64 + mf * 16 + q15;
            af[mf] = *(const short8*)&As[row * 32 + ((h ^ (row & 3)) * 8)];
        }
        #pragma unroll
        for (int nf = 0; nf < 4; ++nf) {
            int row = wn * 64 + nf * 16 + q15;
            bfr[nf] = *(const short8*)&Bs[row * 32 + ((h ^ (row & 3)) * 8)];
        }
        #pragma unroll
        for (int mf = 0; mf < 4; ++mf)
            #pragma unroll
            for (int nf = 0; nf < 4; ++nf)
                acc[mf][nf] = __builtin_amdgcn_mfma_f32_16x16x32_bf16(af[mf], bfr[nf], acc[mf][nf], 0, 0, 0);
        __syncthreads();
    }
    float* Cf = (float*)Cout;
    u16*   Cb = (u16*)Cout;
    #pragma unroll
    for (int mf = 0; mf < 4; ++mf) {
        int mbase = bm + wm * 64 + mf * 16 + h * 4;
        #pragma unroll
        for (int nf = 0; nf < 4; ++nf) {
            int n = bn + wn * 64 + nf * 16 + q15;
            float bv = bias[n];
            #pragma unroll
            for (int rg = 0; rg < 4; ++rg) {
                float val = acc[mf][nf][rg] + bv;
                if (ACT == 1) val = 0.5f * val * (1.f + erff(val * 0.70710678118654752f));
                if (OBF) Cb[(size_t)(mbase + rg) * N + n] = f2bf(val);
                else     Cf[(size_t)(mbase + rg) * N + n] = val;
            }
        }
    }
}

// ---------------- fused local-window flash attention (MFMA) ----------------
// one block per (b, h, 64-query tile); QKV bf16 row-major [B*S][3840]
// (cols: Q 0..767, K 768..1535, V 1536..2303)
__global__ __launch_bounds__(256) void attn_local_mfma(
    const u16* __restrict__ QKV, const int* __restrict__ mask,
    u16* __restrict__ AO) {
    __shared__ __align__(16) u16 Qs[64 * 64];
    __shared__ __align__(16) u16 Ks[64 * 64];
    __shared__ __align__(16) u16 Vst[64 * 64];   // transposed: [d][key], swizzled
    __shared__ __align__(16) u16 Pld[4][16 * 64];
    __shared__ float msk[64];
    int bid = blockIdx.x;
    int qt = bid & 15;
    int hh = (bid >> 4) % HH;
    int b  = bid / (16 * HH);
    int t = threadIdx.x, lane = t & 63, wv = t >> 6;
    int h = lane >> 4, q15 = lane & 15;
    int i0 = qt * 64;

    // stage Q (swizzled source, linear LDS dest)
    #pragma unroll
    for (int op = 0; op < 2; ++op) {
        int r = wv * 16 + op * 8 + (lane >> 3), s = lane & 7;
        gld16(QKV + (size_t)(b * SS + i0 + r) * LD5 + hh * 64 + ((s ^ (r & 7)) * 8),
              &Qs[(wv * 16 + op * 8) * 64]);
    }
    __syncthreads();
    // hoist Q B-fragments (per-wave rows)
    short8 bq[2];
    {
        int qrow = wv * 16 + q15;
        #pragma unroll
        for (int ks = 0; ks < 2; ++ks)
            bq[ks] = *(const short8*)&Qs[qrow * 64 + (((ks * 4 + h) ^ (qrow & 7)) * 8)];
    }

    float mrun = -3e38f, lrun = 0.f;
    f32x4 o[4];
    #pragma unroll
    for (int nf = 0; nf < 4; ++nf) { o[nf][0] = 0.f; o[nf][1] = 0.f; o[nf][2] = 0.f; o[nf][3] = 0.f; }

    int jlo = i0 - W1; if (jlo < 0) jlo = 0;
    int jend = i0 + 64 + W1; if (jend > SS) jend = SS;   // exclusive
    int hasCLS = (jlo > 0) ? 1 : 0;
    int nt = hasCLS + (jend - jlo) / 64;
    int iq = i0 + wv * 16 + q15;   // this lane's query row

    for (int tt = 0; tt < nt; ++tt) {
        int base = (hasCLS && tt == 0) ? 0 : jlo + (tt - hasCLS) * 64;
        if (tt > 0) __syncthreads();
        // stage K (swizzled rows)
        #pragma unroll
        for (int op = 0; op < 2; ++op) {
            int r = wv * 16 + op * 8 + (lane >> 3), s = lane & 7;
            gld16(QKV + (size_t)(b * SS + base + r) * LD5 + 768 + hh * 64 + ((s ^ (r & 7)) * 8),
                  &Ks[(wv * 16 + op * 8) * 64]);
        }
        // stage V transposed: thread handles keys {2k2, 2k2+1}, 8 d's
        {
            int k2 = t & 31, dsec = t >> 5;
            const u16* vp = QKV + (size_t)(b * SS + base + 2 * k2) * LD5 + 1536 + hh * 64 + dsec * 8;
            union { uint4 v; u16 e[8]; } r0, r1;
            r0.v = *(const uint4*)vp;
            r1.v = *(const uint4*)(vp + LD5);
            int slot = k2 >> 2;
            #pragma unroll
            for (int j = 0; j < 8; ++j) {
                int d = dsec * 8 + j;
                unsigned val = (unsigned)r0.e[j] | ((unsigned)r1.e[j] << 16);
                *(unsigned*)&Vst[d * 64 + ((slot ^ (d & 7)) * 8) + ((2 * k2) & 7)] = val;
            }
        }
        if (t < 64) msk[t] = (float)mask[b * SS + base + t];
        __syncthreads();

        // S^T = K @ Q^T  (A = K rows, B = Q rows-as-B^T)
        f32x4 sacc[4];
        #pragma unroll
        for (int kf = 0; kf < 4; ++kf) { sacc[kf][0] = 0.f; sacc[kf][1] = 0.f; sacc[kf][2] = 0.f; sacc[kf][3] = 0.f; }
        #pragma unroll
        for (int ks = 0; ks < 2; ++ks) {
            #pragma unroll
            for (int kf = 0; kf < 4; ++kf) {
                int krow = kf * 16 + q15;
                short8 afr = *(const short8*)&Ks[krow * 64 + (((ks * 4 + h) ^ (krow & 7)) * 8)];
                sacc[kf] = __builtin_amdgcn_mfma_f32_16x16x32_bf16(afr, bq[ks], sacc[kf], 0, 0, 0);
            }
        }
        // mask + scale + online softmax (row = query = q15)
        float pv[4][4];
        float tmax = -3e38f;
        #pragma unroll
        for (int kf = 0; kf < 4; ++kf) {
            #pragma unroll
            for (int rg = 0; rg < 4; ++rg) {
                int kl = kf * 16 + h * 4 + rg;
                int key = base + kl;
                int dj = iq - key; int adj = dj < 0 ? -dj : dj;
                bool valid = ((adj <= W1) || (key == 0)) && (msk[kl] != 0.f);
                float s = valid ? sacc[kf][rg] * SCALE : NEGV;
                pv[kf][rg] = s;
                tmax = fmaxf(tmax, s);
            }
        }
        tmax = fmaxf(tmax, __shfl_xor(tmax, 16));
        tmax = fmaxf(tmax, __shfl_xor(tmax, 32));
        float mnew = fmaxf(mrun, tmax);
        float fac = __expf(mrun - mnew);
        mrun = mnew;
        float psum = 0.f;
        #pragma unroll
        for (int kf = 0; kf < 4; ++kf)
            #pragma unroll
            for (int rg = 0; rg < 4; ++rg) {
                float p = __expf(pv[kf][rg] - mnew);
                pv[kf][rg] = p; psum += p;
            }
        psum += __shfl_xor(psum, 16);
        psum += __shfl_xor(psum, 32);
        lrun = lrun * fac + psum;
        // write P row-major [q][key] into per-wave swizzled LDS
        #pragma unroll
        for (int kf = 0; kf < 4; ++kf) {
            unsigned lo = (unsigned)f2bf(pv[kf][0]) | ((unsigned)f2bf(pv[kf][1]) << 16);
            unsigned hi = (unsigned)f2bf(pv[kf][2]) | ((unsigned)f2bf(pv[kf][3]) << 16);
            int slot = 2 * kf + (h >> 1);
            uint2 w; w.x = lo; w.y = hi;
            *(uint2*)&Pld[wv][q15 * 64 + ((slot ^ (q15 & 7)) * 8) + 4 * (h & 1)] = w;
        }
        // rescale O (O-frag rows are q = 4h+rg -> broadcast fac from lane q)
        float fo0 = __shfl(fac, (h * 4 + 0) | (lane & 48));
        float fo1 = __shfl(fac, (h * 4 + 1) | (lane & 48));
        float fo2 = __shfl(fac, (h * 4 + 2) | (lane & 48));
        float fo3 = __shfl(fac, (h * 4 + 3) | (lane & 48));
        #pragma unroll
        for (int nf = 0; nf < 4; ++nf) {
            o[nf][0] *= fo0; o[nf][1] *= fo1; o[nf][2] *= fo2; o[nf][3] *= fo3;
        }
        asm volatile("s_waitcnt lgkmcnt(0)" ::: "memory");   // P-writes visible to own reads
        // O += P @ V
        #pragma unroll
        for (int ks = 0; ks < 2; ++ks) {
            short8 ap = *(const short8*)&Pld[wv][q15 * 64 + (((ks * 4 + h) ^ (q15 & 7)) * 8)];
            #pragma unroll
            for (int nf = 0; nf < 4; ++nf) {
                int d = nf * 16 + q15;
                short8 bvf = *(const short8*)&Vst[d * 64 + (((ks * 4 + h) ^ (d & 7)) * 8)];
                o[nf] = __builtin_amdgcn_mfma_f32_16x16x32_bf16(ap, bvf, o[nf], 0, 0, 0);
            }
        }
    }
    // finalize
    float linv = 1.f / lrun;
    float g0 = __shfl(linv, (h * 4 + 0) | (lane & 48));
    float g1 = __shfl(linv, (h * 4 + 1) | (lane & 48));
    float g2 = __shfl(linv, (h * 4 + 2) | (lane & 48));
    float g3 = __shfl(linv, (h * 4 + 3) | (lane & 48));
    size_t rb = (size_t)(b * SS + i0 + wv * 16 + h * 4);
    #pragma unroll
    for (int nf = 0; nf < 4; ++nf) {
        int d = hh * 64 + nf * 16 + q15;
        AO[(rb + 0) * DD + d] = f2bf(o[nf][0] * g0);
        AO[(rb + 1) * DD + d] = f2bf(o[nf][1] * g1);
        AO[(rb + 2) * DD + d] = f2bf(o[nf][2] * g2);
        AO[(rb + 3) * DD + d] = f2bf(o[nf][3] * g3);
    }
}

// ---------------- global (CLS) attention, qg GEMV fused in ----------------
// one block per (b, h); KG cols 2304.., VG cols 3072.. of QKV; overwrites AO row 0
__global__ __launch_bounds__(256) void attn_global_kernel(
    const float* __restrict__ Xf, const float* __restrict__ Wqg,
    const float* __restrict__ bqg, const u16* __restrict__ QKV,
    const int* __restrict__ mask, u16* __restrict__ AO) {
    __shared__ float x0[DD];
    __shared__ float qv[64];
    __shared__ float sc[SS];
    __shared__ float red[256];
    __shared__ float part[4][64];
    int b = blockIdx.x / HH, hh = blockIdx.x % HH;
    int t = threadIdx.x;
    // load CLS hidden row (f32)
    #pragma unroll
    for (int i = 0; i < 3; ++i) x0[t + 256 * i] = Xf[(size_t)b * SS * DD + t + 256 * i];
    __syncthreads();
    // qg GEMV: qv[d] = (x0 . Wqg[:, h*64+d] + bqg) * SCALE, 4-way k-split
    {
        int d = t & 63, p = t >> 6;
        float acc = 0.f;
        int k0 = p * 192;
        #pragma unroll 4
        for (int k = k0; k < k0 + 192; ++k)
            acc += x0[k] * Wqg[(size_t)k * DD + hh * 64 + d];
        part[p][d] = acc;
    }
    __syncthreads();
    if (t < 64) qv[t] = (part[0][t] + part[1][t] + part[2][t] + part[3][t] + bqg[hh * 64 + t]) * SCALE;
    __syncthreads();
    // scores over all keys
    for (int j = t; j < SS; j += 256) {
        const u16* kp = QKV + (size_t)(b * SS + j) * LD5 + 2304 + hh * 64;
        float acc = 0.f;
        #pragma unroll
        for (int d0 = 0; d0 < 64; d0 += 8) {
            union { uint4 v; u16 e[8]; } u;
            u.v = *(const uint4*)(kp + d0);
            #pragma unroll
            for (int j2 = 0; j2 < 8; ++j2) acc += qv[d0 + j2] * bf2f(u.e[j2]);
        }
        sc[j] = mask[b * SS + j] ? acc : NEGV;
    }
    __syncthreads();
    float mx = -1e30f;
    for (int j = t; j < SS; j += 256) mx = fmaxf(mx, sc[j]);
    mx = block_reduce_max(mx, red);
    float lsum = 0.f;
    for (int j = t; j < SS; j += 256) {
        float e = __expf(sc[j] - mx);
        sc[j] = e; lsum += e;
    }
    lsum = block_reduce_sum(lsum, red);
    __syncthreads();
    int g = t >> 6, d = t & 63;
    float acc = 0.f;
    for (int j = g; j < SS; j += 4)
        acc += sc[j] * bf2f(QKV[(size_t)(b * SS + j) * LD5 + 3072 + hh * 64 + d]);
    part[g][d] = acc;
    __syncthreads();
    if (g == 0) {
        float ov = (part[0][d] + part[1][d] + part[2][d] + part[3][d]) / lsum;
        AO[(size_t)(b * SS) * DD + hh * 64 + d] = f2bf(ov);
    }
}

// ---------------- classification head, stage A: dvp[b][j] = tanh(hcat . Wd[:,j] + bd) ----------------
__global__ __launch_bounds__(256) void head1_kernel(
    const float* __restrict__ X, const float* __restrict__ motif,
    const float* __restrict__ Wd, const float* __restrict__ bd,
    float* __restrict__ dvp) {
    __shared__ float hc[HCAT];
    __shared__ float part[4][64];
    int jb = blockIdx.x, b = blockIdx.y;
    int t = threadIdx.x;
    for (int i = t; i < DD; i += 256) hc[i] = X[(size_t)b * SS * DD + i];
    for (int i = t; i < MOTIF; i += 256) hc[DD + i] = motif[(size_t)b * MOTIF + i];
    __syncthreads();
    int j = jb * 64 + (t & 63);
    int p = t >> 6;
    int k0 = p * 296, k1 = k0 + 296; if (k1 > HCAT) k1 = HCAT;
    float acc = 0.f;
    for (int k = k0; k < k1; ++k) acc += hc[k] * Wd[(size_t)k * DD + j];
    part[p][t & 63] = acc;
    __syncthreads();
    if (p == 0) {
        int x = t & 63;
        dvp[(size_t)b * DD + j] = tanhf(part[0][x] + part[1][x] + part[2][x] + part[3][x] + bd[j]);
    }
}

// ---------------- head stage B: out[b] = dvp[b] @ Wp + bp ----------------
__global__ __launch_bounds__(256) void head2_kernel(
    const float* __restrict__ dvp, const float* __restrict__ Wp,
    const float* __restrict__ bp, float* __restrict__ out) {
    __shared__ float red[256];
    int b = blockIdx.x;
    int t = threadIdx.x;
    float a0 = 0.f, a1 = 0.f;
    for (int k = t; k < DD; k += 256) {
        float d = dvp[(size_t)b * DD + k];
        a0 += d * Wp[k * 2 + 0];
        a1 += d * Wp[k * 2 + 1];
    }
    a0 = block_reduce_sum(a0, red);
    a1 = block_reduce_sum(a1, red);
    if (t == 0) {
        out[b * 2 + 0] = a0 + bp[0];
        out[b * 2 + 1] = a1 + bp[1];
    }
}

// ---------------- host launch ----------------
extern "C" void kernel_launch(void* const* d_in, const int* in_sizes, int n_in,
                              void* d_out, int out_size, void* d_ws, size_t ws_size,
                              hipStream_t stream) {
    const int*   input_ids = (const int*)d_in[0];
    const int*   attn_mask = (const int*)d_in[1];
    const float* motif     = (const float*)d_in[2];
    const float* emb_word  = (const float*)d_in[3];
    const float* emb_pos   = (const float*)d_in[4];
    const float* emb_type  = (const float*)d_in[5];
    const float* emb_ln_s  = (const float*)d_in[6];
    const float* emb_ln_b  = (const float*)d_in[7];
    const float* Wq  = (const float*)d_in[8];
    const float* bq  = (const float*)d_in[9];
    const float* Wk  = (const float*)d_in[10];
    const float* bk  = (const float*)d_in[11];
    const float* Wv  = (const float*)d_in[12];
    const float* bv  = (const float*)d_in[13];
    const float* Wqg = (const float*)d_in[14];
    const float* bqg = (const float*)d_in[15];
    const float* Wkg = (const float*)d_in[16];
    const float* bkg = (const float*)d_in[17];
    const float* Wvg = (const float*)d_in[18];
    const float* bvg = (const float*)d_in[19];
    const float* Wo  = (const float*)d_in[20];
    const float* bo  = (const float*)d_in[21];
    const float* ln1_s = (const float*)d_in[22];
    const float* ln1_b = (const float*)d_in[23];
    const float* Wi  = (const float*)d_in[24];
    const float* bi  = (const float*)d_in[25];
    const float* Wo2 = (const float*)d_in[26];
    const float* bo2 = (const float*)d_in[27];
    const float* ln2_s = (const float*)d_in[28];
    const float* ln2_b = (const float*)d_in[29];
    const float* head_Wd = (const float*)d_in[30];
    const float* head_bd = (const float*)d_in[31];
    const float* head_Wp = (const float*)d_in[32];
    const float* head_bp = (const float*)d_in[33];

    float* out = (float*)d_out;
    char* base = (char*)d_ws;

    // workspace layout (bytes)
    float* Xf   = (float*)(base + 0);          // [2048][768] f32   6291456
    u16*   Xb   = (u16*)  (base + 6291456);    // [2048][768] bf16  3145728
    u16*   QKVb = (u16*)  (base + 9437184);    // [2048][3840] bf16 15728640
    u16*   AOb  = (u16*)  (base + 25165824);   // [2048][768] bf16  3145728
    float* T1f  = (float*)(base + 28311552);   // [2048][768] f32   6291456
    u16*   Wt6  = (u16*)  (base + 34603008);   // 6 x [768][768] bf16 7077888
    u16*   Wti  = (u16*)  (base + 41680896);   // [3072][768] bf16  4718592
    u16*   Wto2 = (u16*)  (base + 46399488);   // [768][3072] bf16  4718592
    float* bcat = (float*)(base + 51118080);   // [12][3840] f32    184320
    float* dvp  = (float*)(base + 51302400);   // [2][768] f32      6144
    u16*   Hb   = QKVb;                        // FF intermediate aliases QKV

    const int nrow = BB * SS;   // 2048
    embed_ln_kernel<<<nrow, 256, 0, stream>>>(input_ids, emb_word, emb_pos, emb_type,
                                              emb_ln_s, emb_ln_b, Xf, Xb);
    bcat_kernel<<<(LL * LD5 + 255) / 256, 256, 0, stream>>>(bq, bk, bv, bkg, bvg, bcat);

    dim3 g5(30, 16);     // N=3840 batched QKV
    dim3 g768(6, 16);    // N=768 tiles
    dim3 gFF(24, 16);    // N=3072 tiles

    for (int l = 0; l < LL; ++l) {
        size_t oDD = (size_t)l * DD * DD;
        conv6_kernel<<<dim3(24, 24, 6), 256, 0, stream>>>(
            Wq + oDD, Wk + oDD, Wv + oDD, Wkg + oDD, Wvg + oDD, Wo + oDD, Wt6);
        convw_t<<<dim3(96, 24), 256, 0, stream>>>(Wi + (size_t)l * DD * FFF, Wti, DD, FFF);
        convw_t<<<dim3(24, 96), 256, 0, stream>>>(Wo2 + (size_t)l * FFF * DD, Wto2, FFF, DD);

        // batched Q|K|V|KG|VG projection
        gemm_bf16<0, 1><<<g5, 256, 0, stream>>>(Xb, Wt6, bcat + l * LD5, QKVb, nrow, LD5, DD);

        attn_local_mfma<<<BB * HH * 16, 256, 0, stream>>>(QKVb, attn_mask, AOb);
        attn_global_kernel<<<BB * HH, 256, 0, stream>>>(Xf, Wqg + oDD, bqg + l * DD,
                                                        QKVb, attn_mask, AOb);

        gemm_bf16<0, 0><<<g768, 256, 0, stream>>>(AOb, Wt6 + 5 * (size_t)DD * DD, bo + l * DD, T1f, nrow, DD, DD);
        add_ln_kernel<<<nrow, 256, 0, stream>>>(Xf, Xb, T1f, ln1_s + l * DD, ln1_b + l * DD);

        gemm_bf16<1, 1><<<gFF, 256, 0, stream>>>(Xb, Wti, bi + l * FFF, Hb, nrow, FFF, DD);
        gemm_bf16<0, 0><<<g768, 256, 0, stream>>>(Hb, Wto2, bo2 + l * DD, T1f, nrow, DD, FFF);
        add_ln_kernel<<<nrow, 256, 0, stream>>>(Xf, Xb, T1f, ln2_s + l * DD, ln2_b + l * DD);
    }

    head1_kernel<<<dim3(12, BB), 256, 0, stream>>>(Xf, motif, head_Wd, head_bd, dvp);
    head2_kernel<<<BB, 256, 0, stream>>>(dvp, head_Wp, head_bp, out);
}

// Round 5
// 2706.735 us; speedup vs baseline: 6.5065x; 1.3838x over previous
//
#include <hip/hip_runtime.h>
#include <math.h>

typedef unsigned short u16;
typedef __attribute__((ext_vector_type(8))) short short8;   // 8 bf16 (4 VGPRs)
typedef __attribute__((ext_vector_type(4))) float f32x4;

#define BB 2
#define SS 1024
#define LL 12
#define HH 12
#define DD 768
#define FFF 3072
#define MOTIF 414
#define HCAT (DD + MOTIF)
#define W1 256
#define NEGV -1e9f
#define EPS 1e-5f
#define SCALE 0.125f
#define LD5 3840            // 5*768, QKV buffer row stride

// ---------- bf16 helpers ----------
__device__ __forceinline__ float bf2f(u16 u) {
    union { unsigned i; float f; } x; x.i = ((unsigned)u) << 16; return x.f;
}
__device__ __forceinline__ u16 f2bf(float f) {
    union { float f; unsigned i; } x; x.f = f;
    unsigned r = x.i + 0x7fffu + ((x.i >> 16) & 1u);   // RNE
    return (u16)(r >> 16);
}

// async global->LDS, 16B per lane; lds dest must be wave-uniform base
__device__ __forceinline__ void gld16(const u16* g, u16* l) {
    __builtin_amdgcn_global_load_lds((const __attribute__((address_space(1))) void*)g,
                                     (__attribute__((address_space(3))) void*)l, 16, 0, 0);
}

// ---------------- block reduction helpers (blockDim.x == 256) ----------------
__device__ __forceinline__ float block_reduce_sum(float v, float* red) {
    int t = threadIdx.x;
    red[t] = v; __syncthreads();
    #pragma unroll
    for (int s = 128; s > 0; s >>= 1) {
        if (t < s) red[t] += red[t + s];
        __syncthreads();
    }
    float r = red[0]; __syncthreads();
    return r;
}

// ---------------- embedding + LN (writes f32 X and bf16 Xb) ----------------
__global__ __launch_bounds__(256) void embed_ln_kernel(
    const int* __restrict__ ids, const float* __restrict__ ew,
    const float* __restrict__ ep, const float* __restrict__ et,
    const float* __restrict__ gs, const float* __restrict__ gb,
    float* __restrict__ X, u16* __restrict__ Xb) {
    __shared__ float red[256];
    int row = blockIdx.x;
    int s = row % SS;
    int id = ids[row];
    int t = threadIdx.x;
    float v[3];
    float sum = 0.f;
    #pragma unroll
    for (int i = 0; i < 3; ++i) {
        int d = t + 256 * i;
        float x = ew[(size_t)id * DD + d] + ep[(size_t)(s + 2) * DD + d] + et[d];
        v[i] = x; sum += x;
    }
    sum = block_reduce_sum(sum, red);
    float m = sum * (1.f / DD);
    float sq = 0.f;
    #pragma unroll
    for (int i = 0; i < 3; ++i) { float c = v[i] - m; sq += c * c; }
    sq = block_reduce_sum(sq, red);
    float inv = rsqrtf(sq * (1.f / DD) + EPS);
    #pragma unroll
    for (int i = 0; i < 3; ++i) {
        int d = t + 256 * i;
        float o = (v[i] - m) * inv * gs[d] + gb[d];
        X[(size_t)row * DD + d] = o;
        Xb[(size_t)row * DD + d] = f2bf(o);
    }
}

// ---------------- residual add + LN: X = LN(X + T1 [+ T2]); writes f32 + bf16 ----------------
__global__ __launch_bounds__(256) void add_ln_kernel(
    float* __restrict__ X, u16* __restrict__ Xb,
    const float* __restrict__ T1, const float* __restrict__ T2, int useT2,
    const float* __restrict__ gs, const float* __restrict__ gb) {
    __shared__ float red[256];
    int row = blockIdx.x;
    int t = threadIdx.x;
    float v[3];
    float sum = 0.f;
    #pragma unroll
    for (int i = 0; i < 3; ++i) {
        int d = t + 256 * i;
        size_t idx = (size_t)row * DD + d;
        float x = X[idx] + T1[idx] + (useT2 ? T2[idx] : 0.f);
        v[i] = x; sum += x;
    }
    sum = block_reduce_sum(sum, red);
    float m = sum * (1.f / DD);
    float sq = 0.f;
    #pragma unroll
    for (int i = 0; i < 3; ++i) { float c = v[i] - m; sq += c * c; }
    sq = block_reduce_sum(sq, red);
    float inv = rsqrtf(sq * (1.f / DD) + EPS);
    #pragma unroll
    for (int i = 0; i < 3; ++i) {
        int d = t + 256 * i;
        float o = (v[i] - m) * inv * gs[d] + gb[d];
        X[(size_t)row * DD + d] = o;
        Xb[(size_t)row * DD + d] = f2bf(o);
    }
}

// ---------------- merged per-layer weight convert+transpose ----------------
// tiles: [0,3456) six DDxDD -> Wt6 ; [3456,5760) Wi [768,3072]->Wti[3072][768] ;
// [5760,8064) Wo2 [3072,768]->Wto2[768][3072]
__global__ __launch_bounds__(256) void conv_all_kernel(
    const float* __restrict__ w0, const float* __restrict__ w1,
    const float* __restrict__ w2, const float* __restrict__ w3,
    const float* __restrict__ w4, const float* __restrict__ w5,
    const float* __restrict__ wi, const float* __restrict__ wo2,
    u16* __restrict__ Wt6, u16* __restrict__ Wti, u16* __restrict__ Wto2) {
    __shared__ float Tt[32][33];
    int tid = blockIdx.x;
    const float* W; u16* Wt; int Nd, Kd, n0, k0;
    if (tid < 3456) {
        int z = tid / 576, rem = tid % 576;
        W = (z == 0) ? w0 : (z == 1) ? w1 : (z == 2) ? w2 : (z == 3) ? w3 : (z == 4) ? w4 : w5;
        Wt = Wt6 + (size_t)z * DD * DD;
        Nd = DD; Kd = DD; n0 = (rem % 24) * 32; k0 = (rem / 24) * 32;
    } else if (tid < 5760) {
        int i = tid - 3456;
        W = wi; Wt = Wti; Nd = FFF; Kd = DD; n0 = (i % 96) * 32; k0 = (i / 96) * 32;
    } else {
        int i = tid - 5760;
        W = wo2; Wt = Wto2; Nd = DD; Kd = FFF; n0 = (i % 24) * 32; k0 = (i / 24) * 32;
    }
    int t = threadIdx.x;
    int r = t >> 3, c = (t & 7) * 4;
    float4 v = *(const float4*)(W + (size_t)(k0 + r) * Nd + n0 + c);
    Tt[r][c] = v.x; Tt[r][c + 1] = v.y; Tt[r][c + 2] = v.z; Tt[r][c + 3] = v.w;
    __syncthreads();
    int n = t >> 3, k4 = (t & 7) * 4;
    unsigned lo = (unsigned)f2bf(Tt[k4][n])     | ((unsigned)f2bf(Tt[k4 + 1][n]) << 16);
    unsigned hi = (unsigned)f2bf(Tt[k4 + 2][n]) | ((unsigned)f2bf(Tt[k4 + 3][n]) << 16);
    uint2 wv; wv.x = lo; wv.y = hi;
    *(uint2*)&Wt[(size_t)(n0 + n) * Kd + k0 + k4] = wv;
}

// ---------------- bias concat for batched QKV gemm: bcat[l][5*768] ----------------
__global__ __launch_bounds__(256) void bcat_kernel(
    const float* __restrict__ bq, const float* __restrict__ bk,
    const float* __restrict__ bv, const float* __restrict__ bkg,
    const float* __restrict__ bvg, float* __restrict__ bcat) {
    int tid = blockIdx.x * 256 + threadIdx.x;
    if (tid >= LL * LD5) return;
    int l = tid / LD5, r = tid % LD5, z = r / DD, j = r % DD;
    const float* src = (z == 0) ? bq : (z == 1) ? bk : (z == 2) ? bv : (z == 3) ? bkg : bvg;
    bcat[tid] = src[l * DD + j];
}

// ---------------- bf16 MFMA GEMM: C = A[M,K] @ Bt[N,K]^T + bias, optional split-K ----------------
// ACT: 0 none, 1 exact gelu (only valid without split).  OBF: 1 bf16 out, 0 f32 out.
// blockIdx.z selects K-half: z=0 -> C0 (+bias), z=1 -> C1 (no bias).
template <int ACT, int OBF>
__global__ __launch_bounds__(256) void gemm_bf16(
    const u16* __restrict__ A, const u16* __restrict__ Bt,
    const float* __restrict__ bias, void* __restrict__ C0, void* __restrict__ C1,
    int M, int N, int K, int Ksplit) {
    __shared__ __align__(16) u16 As[128 * 32];
    __shared__ __align__(16) u16 Bs[128 * 32];
    int z = blockIdx.z;
    int kbeg = z * Ksplit;
    int kend = kbeg + Ksplit; if (kend > K) kend = K;
    void* Cout = z ? C1 : C0;
    int t = threadIdx.x, lane = t & 63, wv = t >> 6;
    int bm = blockIdx.y * 128, bn = blockIdx.x * 128;
    int wm = wv >> 1, wn = wv & 1;
    int h = lane >> 4, q15 = lane & 15;
    f32x4 acc[4][4];
    #pragma unroll
    for (int i = 0; i < 4; ++i)
        #pragma unroll
        for (int j = 0; j < 4; ++j) { acc[i][j][0] = 0.f; acc[i][j][1] = 0.f; acc[i][j][2] = 0.f; acc[i][j][3] = 0.f; }

    for (int k0 = kbeg; k0 < kend; k0 += 32) {
        #pragma unroll
        for (int op = 0; op < 2; ++op) {
            int rc = wv * 32 + op * 16;
            int r = rc + (lane >> 2), s = lane & 3;
            gld16(A  + (size_t)(bm + r) * K + k0 + ((s ^ (r & 3)) * 8), &As[rc * 32]);
            gld16(Bt + (size_t)(bn + r) * K + k0 + ((s ^ (r & 3)) * 8), &Bs[rc * 32]);
        }
        __syncthreads();
        short8 af[4], bfr[4];
        #pragma unroll
        for (int mf = 0; mf < 4; ++mf) {
            int row = wm * 64 + mf * 16 + q15;
            af[mf] = *(const short8*)&As[row * 32 + ((h ^ (row & 3)) * 8)];
        }
        #pragma unroll
        for (int nf = 0; nf < 4; ++nf) {
            int row = wn * 64 + nf * 16 + q15;
            bfr[nf] = *(const short8*)&Bs[row * 32 + ((h ^ (row & 3)) * 8)];
        }
        #pragma unroll
        for (int mf = 0; mf < 4; ++mf)
            #pragma unroll
            for (int nf = 0; nf < 4; ++nf)
                acc[mf][nf] = __builtin_amdgcn_mfma_f32_16x16x32_bf16(af[mf], bfr[nf], acc[mf][nf], 0, 0, 0);
        __syncthreads();
    }
    float* Cf = (float*)Cout;
    u16*   Cb = (u16*)Cout;
    #pragma unroll
    for (int mf = 0; mf < 4; ++mf) {
        int mbase = bm + wm * 64 + mf * 16 + h * 4;
        #pragma unroll
        for (int nf = 0; nf < 4; ++nf) {
            int n = bn + wn * 64 + nf * 16 + q15;
            float bv = 0.f;
            if (z == 0) bv = bias[n];
            #pragma unroll
            for (int rg = 0; rg < 4; ++rg) {
                float val = acc[mf][nf][rg] + bv;
                if (ACT == 1) val = 0.5f * val * (1.f + erff(val * 0.70710678118654752f));
                if (OBF) Cb[(size_t)(mbase + rg) * N + n] = f2bf(val);
                else     Cf[(size_t)(mbase + rg) * N + n] = val;
            }
        }
    }
}

// ---------------- fused local-window flash attention (MFMA) ----------------
// one block per (b, h, 64-query tile); QKV bf16 row-major [B*S][3840]
// (cols: Q 0..767, K 768..1535, V 1536..2303)
__global__ __launch_bounds__(256) void attn_local_mfma(
    const u16* __restrict__ QKV, const int* __restrict__ mask,
    u16* __restrict__ AO) {
    __shared__ __align__(16) u16 Qs[64 * 64];
    __shared__ __align__(16) u16 Ks[64 * 64];
    __shared__ __align__(16) u16 Vst[64 * 64];   // transposed: [d][key], swizzled
    __shared__ __align__(16) u16 Pld[4][16 * 64];
    __shared__ float msk[64];
    int bid = blockIdx.x;
    int qt = bid & 15;
    int hh = (bid >> 4) % HH;
    int b  = bid / (16 * HH);
    int t = threadIdx.x, lane = t & 63, wv = t >> 6;
    int h = lane >> 4, q15 = lane & 15;
    int i0 = qt * 64;

    // stage Q (swizzled source, linear LDS dest)
    #pragma unroll
    for (int op = 0; op < 2; ++op) {
        int r = wv * 16 + op * 8 + (lane >> 3), s = lane & 7;
        gld16(QKV + (size_t)(b * SS + i0 + r) * LD5 + hh * 64 + ((s ^ (r & 7)) * 8),
              &Qs[(wv * 16 + op * 8) * 64]);
    }
    __syncthreads();
    // hoist Q B-fragments (per-wave rows)
    short8 bq[2];
    {
        int qrow = wv * 16 + q15;
        #pragma unroll
        for (int ks = 0; ks < 2; ++ks)
            bq[ks] = *(const short8*)&Qs[qrow * 64 + (((ks * 4 + h) ^ (qrow & 7)) * 8)];
    }

    float mrun = -3e38f, lrun = 0.f;
    f32x4 o[4];
    #pragma unroll
    for (int nf = 0; nf < 4; ++nf) { o[nf][0] = 0.f; o[nf][1] = 0.f; o[nf][2] = 0.f; o[nf][3] = 0.f; }

    int jlo = i0 - W1; if (jlo < 0) jlo = 0;
    int jend = i0 + 64 + W1; if (jend > SS) jend = SS;   // exclusive
    int hasCLS = (jlo > 0) ? 1 : 0;
    int nt = hasCLS + (jend - jlo) / 64;
    int iq = i0 + wv * 16 + q15;   // this lane's query row

    for (int tt = 0; tt < nt; ++tt) {
        int base = (hasCLS && tt == 0) ? 0 : jlo + (tt - hasCLS) * 64;
        if (tt > 0) __syncthreads();
        // stage K (swizzled rows)
        #pragma unroll
        for (int op = 0; op < 2; ++op) {
            int r = wv * 16 + op * 8 + (lane >> 3), s = lane & 7;
            gld16(QKV + (size_t)(b * SS + base + r) * LD5 + 768 + hh * 64 + ((s ^ (r & 7)) * 8),
                  &Ks[(wv * 16 + op * 8) * 64]);
        }
        // stage V transposed: thread handles keys {2k2, 2k2+1}, 8 d's
        {
            int k2 = t & 31, dsec = t >> 5;
            const u16* vp = QKV + (size_t)(b * SS + base + 2 * k2) * LD5 + 1536 + hh * 64 + dsec * 8;
            union { uint4 v; u16 e[8]; } r0, r1;
            r0.v = *(const uint4*)vp;
            r1.v = *(const uint4*)(vp + LD5);
            int slot = k2 >> 2;
            #pragma unroll
            for (int j = 0; j < 8; ++j) {
                int d = dsec * 8 + j;
                unsigned val = (unsigned)r0.e[j] | ((unsigned)r1.e[j] << 16);
                *(unsigned*)&Vst[d * 64 + ((slot ^ (d & 7)) * 8) + ((2 * k2) & 7)] = val;
            }
        }
        if (t < 64) msk[t] = (float)mask[b * SS + base + t];
        __syncthreads();

        // S^T = K @ Q^T  (A = K rows, B = Q rows-as-B^T)
        f32x4 sacc[4];
        #pragma unroll
        for (int kf = 0; kf < 4; ++kf) { sacc[kf][0] = 0.f; sacc[kf][1] = 0.f; sacc[kf][2] = 0.f; sacc[kf][3] = 0.f; }
        #pragma unroll
        for (int ks = 0; ks < 2; ++ks) {
            #pragma unroll
            for (int kf = 0; kf < 4; ++kf) {
                int krow = kf * 16 + q15;
                short8 afr = *(const short8*)&Ks[krow * 64 + (((ks * 4 + h) ^ (krow & 7)) * 8)];
                sacc[kf] = __builtin_amdgcn_mfma_f32_16x16x32_bf16(afr, bq[ks], sacc[kf], 0, 0, 0);
            }
        }
        // mask + scale + online softmax (row = query = q15)
        float pv[4][4];
        float tmax = -3e38f;
        #pragma unroll
        for (int kf = 0; kf < 4; ++kf) {
            #pragma unroll
            for (int rg = 0; rg < 4; ++rg) {
                int kl = kf * 16 + h * 4 + rg;
                int key = base + kl;
                int dj = iq - key; int adj = dj < 0 ? -dj : dj;
                bool valid = ((adj <= W1) || (key == 0)) && (msk[kl] != 0.f);
                float s = valid ? sacc[kf][rg] * SCALE : NEGV;
                pv[kf][rg] = s;
                tmax = fmaxf(tmax, s);
            }
        }
        tmax = fmaxf(tmax, __shfl_xor(tmax, 16));
        tmax = fmaxf(tmax, __shfl_xor(tmax, 32));
        float mnew = fmaxf(mrun, tmax);
        float fac = __expf(mrun - mnew);
        mrun = mnew;
        float psum = 0.f;
        #pragma unroll
        for (int kf = 0; kf < 4; ++kf)
            #pragma unroll
            for (int rg = 0; rg < 4; ++rg) {
                float p = __expf(pv[kf][rg] - mnew);
                pv[kf][rg] = p; psum += p;
            }
        psum += __shfl_xor(psum, 16);
        psum += __shfl_xor(psum, 32);
        lrun = lrun * fac + psum;
        // write P row-major [q][key] into per-wave swizzled LDS
        #pragma unroll
        for (int kf = 0; kf < 4; ++kf) {
            unsigned lo = (unsigned)f2bf(pv[kf][0]) | ((unsigned)f2bf(pv[kf][1]) << 16);
            unsigned hi = (unsigned)f2bf(pv[kf][2]) | ((unsigned)f2bf(pv[kf][3]) << 16);
            int slot = 2 * kf + (h >> 1);
            uint2 w; w.x = lo; w.y = hi;
            *(uint2*)&Pld[wv][q15 * 64 + ((slot ^ (q15 & 7)) * 8) + 4 * (h & 1)] = w;
        }
        // rescale O (O-frag rows are q = 4h+rg -> broadcast fac from lane q)
        float fo0 = __shfl(fac, (h * 4 + 0) | (lane & 48));
        float fo1 = __shfl(fac, (h * 4 + 1) | (lane & 48));
        float fo2 = __shfl(fac, (h * 4 + 2) | (lane & 48));
        float fo3 = __shfl(fac, (h * 4 + 3) | (lane & 48));
        #pragma unroll
        for (int nf = 0; nf < 4; ++nf) {
            o[nf][0] *= fo0; o[nf][1] *= fo1; o[nf][2] *= fo2; o[nf][3] *= fo3;
        }
        asm volatile("s_waitcnt lgkmcnt(0)" ::: "memory");   // P-writes visible to own reads
        // O += P @ V
        #pragma unroll
        for (int ks = 0; ks < 2; ++ks) {
            short8 ap = *(const short8*)&Pld[wv][q15 * 64 + (((ks * 4 + h) ^ (q15 & 7)) * 8)];
            #pragma unroll
            for (int nf = 0; nf < 4; ++nf) {
                int d = nf * 16 + q15;
                short8 bvf = *(const short8*)&Vst[d * 64 + (((ks * 4 + h) ^ (d & 7)) * 8)];
                o[nf] = __builtin_amdgcn_mfma_f32_16x16x32_bf16(ap, bvf, o[nf], 0, 0, 0);
            }
        }
    }
    // finalize
    float linv = 1.f / lrun;
    float g0 = __shfl(linv, (h * 4 + 0) | (lane & 48));
    float g1 = __shfl(linv, (h * 4 + 1) | (lane & 48));
    float g2 = __shfl(linv, (h * 4 + 2) | (lane & 48));
    float g3 = __shfl(linv, (h * 4 + 3) | (lane & 48));
    size_t rb = (size_t)(b * SS + i0 + wv * 16 + h * 4);
    #pragma unroll
    for (int nf = 0; nf < 4; ++nf) {
        int d = hh * 64 + nf * 16 + q15;
        AO[(rb + 0) * DD + d] = f2bf(o[nf][0] * g0);
        AO[(rb + 1) * DD + d] = f2bf(o[nf][1] * g1);
        AO[(rb + 2) * DD + d] = f2bf(o[nf][2] * g2);
        AO[(rb + 3) * DD + d] = f2bf(o[nf][3] * g3);
    }
}

// ---------------- global (CLS) attention, qg GEMV fused, 512 threads ----------------
// one block per (b, h); KG cols 2304.., VG cols 3072..; overwrites AO row 0
__global__ __launch_bounds__(512) void attn_global_kernel(
    const float* __restrict__ Xf, const float* __restrict__ Wqg,
    const float* __restrict__ bqg, const u16* __restrict__ QKV,
    const int* __restrict__ mask, u16* __restrict__ AO) {
    __shared__ float x0[DD];
    __shared__ float qv[64];
    __shared__ float sc[SS];
    __shared__ float red[512];
    __shared__ float part[8][64];
    int b = blockIdx.x / HH, hh = blockIdx.x % HH;
    int t = threadIdx.x;
    for (int i = t; i < DD; i += 512) x0[i] = Xf[(size_t)b * SS * DD + i];
    __syncthreads();
    // qg GEMV, 8-way k-split
    {
        int d = t & 63, p = t >> 6;
        float acc = 0.f;
        int k0 = p * 96;
        #pragma unroll 8
        for (int k = k0; k < k0 + 96; ++k)
            acc += x0[k] * Wqg[(size_t)k * DD + hh * 64 + d];
        part[p][d] = acc;
    }
    __syncthreads();
    if (t < 64) {
        float s = bqg[hh * 64 + t];
        #pragma unroll
        for (int p = 0; p < 8; ++p) s += part[p][t];
        qv[t] = s * SCALE;
    }
    __syncthreads();
    // scores over all keys (2 per thread)
    for (int j = t; j < SS; j += 512) {
        const u16* kp = QKV + (size_t)(b * SS + j) * LD5 + 2304 + hh * 64;
        float acc = 0.f;
        #pragma unroll
        for (int d0 = 0; d0 < 64; d0 += 8) {
            union { uint4 v; u16 e[8]; } u;
            u.v = *(const uint4*)(kp + d0);
            #pragma unroll
            for (int j2 = 0; j2 < 8; ++j2) acc += qv[d0 + j2] * bf2f(u.e[j2]);
        }
        sc[j] = mask[b * SS + j] ? acc : NEGV;
    }
    __syncthreads();
    // softmax over 1024
    float mx = fmaxf(sc[t], sc[t + 512]);
    red[t] = mx; __syncthreads();
    #pragma unroll
    for (int s = 256; s > 0; s >>= 1) {
        if (t < s) red[t] = fmaxf(red[t], red[t + s]);
        __syncthreads();
    }
    mx = red[0]; __syncthreads();
    float e0 = __expf(sc[t] - mx), e1 = __expf(sc[t + 512] - mx);
    sc[t] = e0; sc[t + 512] = e1;
    red[t] = e0 + e1; __syncthreads();
    #pragma unroll
    for (int s = 256; s > 0; s >>= 1) {
        if (t < s) red[t] += red[t + s];
        __syncthreads();
    }
    float lsum = red[0]; __syncthreads();
    // PV, 8-way key split
    int g = t >> 6, d = t & 63;
    float acc = 0.f;
    for (int j = g; j < SS; j += 8)
        acc += sc[j] * bf2f(QKV[(size_t)(b * SS + j) * LD5 + 3072 + hh * 64 + d]);
    part[g][d] = acc;
    __syncthreads();
    if (g == 0) {
        float ov = 0.f;
        #pragma unroll
        for (int p = 0; p < 8; ++p) ov += part[p][d];
        AO[(size_t)(b * SS) * DD + hh * 64 + d] = f2bf(ov / lsum);
    }
}

// ---------------- head stage A: hpart[b][kp][j] = partial(hcat . Wd[:,j]) ----------------
__global__ __launch_bounds__(256) void head1_kernel(
    const float* __restrict__ X, const float* __restrict__ motif,
    const float* __restrict__ Wd, float* __restrict__ hpart) {
    __shared__ float hc[HCAT];
    __shared__ float part[4][64];
    int jb = blockIdx.x, kp = blockIdx.y, b = blockIdx.z;
    int t = threadIdx.x;
    for (int i = t; i < DD; i += 256) hc[i] = X[(size_t)b * SS * DD + i];
    for (int i = t; i < MOTIF; i += 256) hc[DD + i] = motif[(size_t)b * MOTIF + i];
    __syncthreads();
    int j = jb * 64 + (t & 63);
    int sub = t >> 6;
    int k0 = kp * 148 + sub * 37;
    int k1 = k0 + 37; if (k1 > HCAT) k1 = HCAT;
    float acc = 0.f;
    for (int k = k0; k < k1; ++k) acc += hc[k] * Wd[(size_t)k * DD + j];
    part[sub][t & 63] = acc;
    __syncthreads();
    if (sub == 0) {
        int x = t & 63;
        hpart[((size_t)b * 8 + kp) * DD + j] = part[0][x] + part[1][x] + part[2][x] + part[3][x];
    }
}

// ---------------- head stage B: out[b] = tanh(sum partials + bd) @ Wp + bp ----------------
__global__ __launch_bounds__(256) void head2_kernel(
    const float* __restrict__ hpart, const float* __restrict__ bd,
    const float* __restrict__ Wp, const float* __restrict__ bp,
    float* __restrict__ out) {
    __shared__ float dvs[DD];
    __shared__ float red[256];
    int b = blockIdx.x;
    int t = threadIdx.x;
    for (int j = t; j < DD; j += 256) {
        float s = bd[j];
        #pragma unroll
        for (int kp = 0; kp < 8; ++kp) s += hpart[((size_t)b * 8 + kp) * DD + j];
        dvs[j] = tanhf(s);
    }
    __syncthreads();
    float a0 = 0.f, a1 = 0.f;
    for (int k = t; k < DD; k += 256) {
        a0 += dvs[k] * Wp[k * 2 + 0];
        a1 += dvs[k] * Wp[k * 2 + 1];
    }
    a0 = block_reduce_sum(a0, red);
    a1 = block_reduce_sum(a1, red);
    if (t == 0) {
        out[b * 2 + 0] = a0 + bp[0];
        out[b * 2 + 1] = a1 + bp[1];
    }
}

// ---------------- host launch ----------------
extern "C" void kernel_launch(void* const* d_in, const int* in_sizes, int n_in,
                              void* d_out, int out_size, void* d_ws, size_t ws_size,
                              hipStream_t stream) {
    const int*   input_ids = (const int*)d_in[0];
    const int*   attn_mask = (const int*)d_in[1];
    const float* motif     = (const float*)d_in[2];
    const float* emb_word  = (const float*)d_in[3];
    const float* emb_pos   = (const float*)d_in[4];
    const float* emb_type  = (const float*)d_in[5];
    const float* emb_ln_s  = (const float*)d_in[6];
    const float* emb_ln_b  = (const float*)d_in[7];
    const float* Wq  = (const float*)d_in[8];
    const float* bq  = (const float*)d_in[9];
    const float* Wk  = (const float*)d_in[10];
    const float* bk  = (const float*)d_in[11];
    const float* Wv  = (const float*)d_in[12];
    const float* bv  = (const float*)d_in[13];
    const float* Wqg = (const float*)d_in[14];
    const float* bqg = (const float*)d_in[15];
    const float* Wkg = (const float*)d_in[16];
    const float* bkg = (const float*)d_in[17];
    const float* Wvg = (const float*)d_in[18];
    const float* bvg = (const float*)d_in[19];
    const float* Wo  = (const float*)d_in[20];
    const float* bo  = (const float*)d_in[21];
    const float* ln1_s = (const float*)d_in[22];
    const float* ln1_b = (const float*)d_in[23];
    const float* Wi  = (const float*)d_in[24];
    const float* bi  = (const float*)d_in[25];
    const float* Wo2 = (const float*)d_in[26];
    const float* bo2 = (const float*)d_in[27];
    const float* ln2_s = (const float*)d_in[28];
    const float* ln2_b = (const float*)d_in[29];
    const float* head_Wd = (const float*)d_in[30];
    const float* head_bd = (const float*)d_in[31];
    const float* head_Wp = (const float*)d_in[32];
    const float* head_bp = (const float*)d_in[33];

    float* out = (float*)d_out;
    char* base = (char*)d_ws;

    // workspace layout (bytes)
    float* Xf   = (float*)(base + 0);          // [2048][768] f32
    u16*   Xb   = (u16*)  (base + 6291456);    // [2048][768] bf16
    u16*   QKVb = (u16*)  (base + 9437184);    // [2048][3840] bf16
    u16*   AOb  = (u16*)  (base + 25165824);   // [2048][768] bf16
    float* T1f  = (float*)(base + 28311552);   // [2048][768] f32

    const size_t NEED_BIG = 57643008;
    bool big = ws_size >= NEED_BIG;
    float* T2f = big ? (float*)(base + 34603008) : T1f;
    size_t wbase = big ? 40894464 : 34603008;
    u16*   Wt6   = (u16*)  (base + wbase);
    u16*   Wti   = (u16*)  (base + wbase + 7077888);
    u16*   Wto2  = (u16*)  (base + wbase + 11796480);
    float* bcat  = (float*)(base + wbase + 16515072);
    float* hpart = (float*)(base + wbase + 16699392);   // [2][8][768] f32
    u16*   Hb    = QKVb;                                 // FF intermediate aliases QKV

    const int nrow = BB * SS;   // 2048
    const int useT2 = big ? 1 : 0;

    embed_ln_kernel<<<nrow, 256, 0, stream>>>(input_ids, emb_word, emb_pos, emb_type,
                                              emb_ln_s, emb_ln_b, Xf, Xb);
    bcat_kernel<<<(LL * LD5 + 255) / 256, 256, 0, stream>>>(bq, bk, bv, bkg, bvg, bcat);

    dim3 g5(30, 16, 1);                  // N=3840 batched QKV
    dim3 gO(6, 16, big ? 2 : 1);         // N=768, split-K
    dim3 gFF1(24, 16, 1);                // N=3072
    dim3 gFF2(6, 16, big ? 2 : 1);       // N=768, K=3072 split

    for (int l = 0; l < LL; ++l) {
        size_t oDD = (size_t)l * DD * DD;
        conv_all_kernel<<<8064, 256, 0, stream>>>(
            Wq + oDD, Wk + oDD, Wv + oDD, Wkg + oDD, Wvg + oDD, Wo + oDD,
            Wi + (size_t)l * DD * FFF, Wo2 + (size_t)l * FFF * DD,
            Wt6, Wti, Wto2);

        // batched Q|K|V|KG|VG projection
        gemm_bf16<0, 1><<<g5, 256, 0, stream>>>(Xb, Wt6, bcat + l * LD5, QKVb, QKVb,
                                                nrow, LD5, DD, DD);

        attn_local_mfma<<<BB * HH * 16, 256, 0, stream>>>(QKVb, attn_mask, AOb);
        attn_global_kernel<<<BB * HH, 512, 0, stream>>>(Xf, Wqg + oDD, bqg + l * DD,
                                                        QKVb, attn_mask, AOb);

        gemm_bf16<0, 0><<<gO, 256, 0, stream>>>(AOb, Wt6 + 5 * (size_t)DD * DD, bo + l * DD,
                                                T1f, T2f, nrow, DD, DD, big ? 384 : 768);
        add_ln_kernel<<<nrow, 256, 0, stream>>>(Xf, Xb, T1f, T2f, useT2,
                                                ln1_s + l * DD, ln1_b + l * DD);

        gemm_bf16<1, 1><<<gFF1, 256, 0, stream>>>(Xb, Wti, bi + l * FFF, Hb, Hb,
                                                  nrow, FFF, DD, DD);
        gemm_bf16<0, 0><<<gFF2, 256, 0, stream>>>(Hb, Wto2, bo2 + l * DD,
                                                  T1f, T2f, nrow, DD, FFF, big ? 1536 : 3072);
        add_ln_kernel<<<nrow, 256, 0, stream>>>(Xf, Xb, T1f, T2f, useT2,
                                                ln2_s + l * DD, ln2_b + l * DD);
    }

    head1_kernel<<<dim3(12, 8, BB), 256, 0, stream>>>(Xf, motif, head_Wd, hpart);
    head2_kernel<<<BB, 256, 0, stream>>>(hpart, head_Wp ? head_bd : head_bd, head_Wp, head_bp, out);
}